// Round 3
// baseline (283.717 us; speedup 1.0000x reference)
//
#include <hip/hip_runtime.h>
#include <hip/hip_fp16.h>
#include <math.h>

#define N_NODES 50000
#define N_EDGES 800000
#define ET (N_EDGES + N_NODES)   // edges + self loops
#define NEG_SLOPE 0.2f

// binned scatter params: 256-node buckets
#define BSHIFT 8
#define NBUK ((N_NODES + 255) >> BSHIFT)    // 196 buckets
#define BCAP 4608                           // per-bucket capacity (mean 4096, +8 sigma)
#define ACHUNK 4096                         // edges per k_bin block

typedef __attribute__((ext_vector_type(8))) short s16x8;
typedef __attribute__((ext_vector_type(4))) float f32x4;
typedef __attribute__((ext_vector_type(2))) float f32x2;

__device__ __forceinline__ unsigned short f2bf(float f) {
    union { float f; unsigned u; } v; v.f = f;
    unsigned r = v.u + 0x7FFF + ((v.u >> 16) & 1);  // RNE
    return (unsigned short)(r >> 16);
}
__device__ __forceinline__ float bf2f(unsigned short s) {
    union { unsigned u; float f; } v; v.u = ((unsigned)s) << 16;
    return v.f;
}
__device__ __forceinline__ unsigned short f2h(float f) {
    union { _Float16 h; unsigned short s; } v; v.h = (_Float16)f; return v.s;
}
__device__ __forceinline__ float h2f(unsigned short s) {
    union { unsigned short s; _Float16 h; } v; v.s = s; return (float)v.h;
}
// truncation-pack 8 fp32 -> 8 bf16
__device__ __forceinline__ uint4 pack_bf16_trunc(float4 f0, float4 f1) {
    const unsigned* a = (const unsigned*)&f0;
    const unsigned* b = (const unsigned*)&f1;
    uint4 r;
    r.x = (a[0] >> 16) | (a[1] & 0xffff0000u);
    r.y = (a[2] >> 16) | (a[3] & 0xffff0000u);
    r.z = (b[0] >> 16) | (b[1] & 0xffff0000u);
    r.w = (b[2] >> 16) | (b[3] & 0xffff0000u);
    return r;
}
// fp8 e4m3 (OCP) — HW convert
__device__ __forceinline__ unsigned char f2fp8(float f) {
    return (unsigned char)(__builtin_amdgcn_cvt_pk_fp8_f32(f, f, 0, false) & 0xff);
}

// ---------------- weight converts + bcur zeroing (fused; runs first) ----------------

__global__ __launch_bounds__(256) void k_cvtw(const float* __restrict__ W1, const float* __restrict__ W2,
                                              unsigned short* __restrict__ WT, unsigned short* __restrict__ W2T,
                                              int* __restrict__ bcur) {
    int b = blockIdx.x, k = threadIdx.x;
    if (b < 256) {
        WT[b * 256 + k] = f2bf(W1[k * 256 + b]);
    } else if (b < 288) {
        int c = b - 256;
        W2T[c * 256 + k] = f2bf(W2[k * 32 + c]);
    } else {
        if (k < NBUK) bcur[k] = 0;
    }
}

// ---------------- Phase A: LDS-binned edge staging ----------------

__global__ __launch_bounds__(256) void k_bin(const int* __restrict__ ei, int* __restrict__ bcur,
                                             unsigned* __restrict__ stage) {
    __shared__ unsigned sdata[ACHUNK];        // packed u | vloc<<16, bucket-major
    __shared__ unsigned short sv[ACHUNK];     // v cached between passes (v < 65536)
    __shared__ int scnt[NBUK];                // counts, then pass-2 cursors
    __shared__ int soff[NBUK + 1];            // exclusive scan
    __shared__ int sgbase[NBUK];              // global base per bucket
    __shared__ int wssc[4];
    int tid = threadIdx.x;
    int e0 = blockIdx.x * ACHUNK;
    int nE = N_EDGES - e0;
    if (nE > ACHUNK) nE = ACHUNK;
    for (int i = tid; i < NBUK; i += 256) scnt[i] = 0;
    __syncthreads();
    for (int i = tid; i < nE; i += 256) {
        int v = ei[N_EDGES + e0 + i];
        sv[i] = (unsigned short)v;
        atomicAdd(&scnt[v >> BSHIFT], 1);
    }
    __syncthreads();
    {
        int lane = tid & 63, w = tid >> 6;
        int val = (tid < NBUK) ? scnt[tid] : 0;
        int incl = val;
        for (int o = 1; o < 64; o <<= 1) {
            int t = __shfl_up(incl, o);
            if (lane >= o) incl += t;
        }
        if (lane == 63) wssc[w] = incl;
        __syncthreads();
        int wb = 0;
        for (int i = 0; i < w; ++i) wb += wssc[i];
        if (tid < NBUK) soff[tid] = wb + incl - val;
        if (tid == 255) soff[NBUK] = wb + incl;
    }
    __syncthreads();
    if (tid < NBUK) {
        int c = scnt[tid];
        sgbase[tid] = c ? atomicAdd(&bcur[tid], c) : 0;
        scnt[tid] = soff[tid];
    }
    __syncthreads();
    for (int i = tid; i < nE; i += 256) {
        int u = ei[e0 + i];
        unsigned v = sv[i];
        int b = (int)(v >> BSHIFT);
        int pos = atomicAdd(&scnt[b], 1);
        sdata[pos] = (unsigned)u | ((v & 255u) << 16);
    }
    __syncthreads();
    for (int i = tid; i < nE; i += 256) {
        int lo = 0, hi = NBUK - 1;
        while (lo < hi) {
            int mid = (lo + hi + 1) >> 1;
            if (soff[mid] <= i) lo = mid; else hi = mid - 1;
        }
        int rel = sgbase[lo] + (i - soff[lo]);
        if (rel < BCAP) stage[(size_t)lo * BCAP + rel] = sdata[i];
    }
}

// ---------------- bucket-base scan (1 block; also writes off[N]) ----------------

__global__ __launch_bounds__(256) void k_bukscan(const int* __restrict__ bcur, int* __restrict__ bukbase,
                                                 int* __restrict__ off) {
    __shared__ int ws[4];
    int tid = threadIdx.x, lane = tid & 63, w = tid >> 6;
    int val = 0;
    if (tid < NBUK) {
        int base = tid << BSHIFT;
        int nv = N_NODES - base;
        if (nv > 256) nv = 256;
        val = bcur[tid] + nv;   // edges + self-loops in this bucket
    }
    int incl = val;
    for (int o = 1; o < 64; o <<= 1) {
        int t = __shfl_up(incl, o);
        if (lane >= o) incl += t;
    }
    if (lane == 63) ws[w] = incl;
    __syncthreads();
    int wb = 0;
    for (int i = 0; i < w; ++i) wb += ws[i];
    if (tid < NBUK) bukbase[tid] = wb + incl - val;
    if (tid == 0) off[N_NODES] = ET;
}

// ---------------- Phase B: per-bucket CSR build (esrc as u16) ----------------

__global__ __launch_bounds__(256) void k_build(const unsigned* __restrict__ stage,
                                               const int* __restrict__ bcur, const int* __restrict__ bukbase,
                                               int* __restrict__ off, unsigned short* __restrict__ esrc) {
    __shared__ int hist[256];            // counts, then per-node cursors
    __shared__ int lexcl[257];
    __shared__ int ws[4];
    __shared__ int outbuf[BCAP + 256];
    int b = blockIdx.x, tid = threadIdx.x;
    int n = bcur[b];
    if (n > BCAP) n = BCAP;
    int base = b << BSHIFT;
    int nv = N_NODES - base;
    if (nv > 256) nv = 256;
    hist[tid] = 0;
    __syncthreads();
    const unsigned* sg = stage + (size_t)b * BCAP;
    for (int i = tid; i < n; i += 256) atomicAdd(&hist[sg[i] >> 16], 1);
    __syncthreads();
    int lane = tid & 63, w = tid >> 6;
    int val = (tid < nv) ? hist[tid] + 1 : 0;
    int incl = val;
    for (int o = 1; o < 64; o <<= 1) {
        int t = __shfl_up(incl, o);
        if (lane >= o) incl += t;
    }
    if (lane == 63) ws[w] = incl;
    __syncthreads();
    int wb = 0;
    for (int i = 0; i < w; ++i) wb += ws[i];
    int excl = wb + incl - val;
    lexcl[tid] = excl;
    if (tid == 255) lexcl[256] = excl + val;   // total = n + nv
    int gb = bukbase[b];
    if (tid < nv) off[base + tid] = gb + excl;
    __syncthreads();
    int total = lexcl[256];
    if (tid < nv) {
        outbuf[excl] = base + tid;   // self-loop first
        hist[tid] = 1;
    }
    __syncthreads();
    for (int i = tid; i < n; i += 256) {
        unsigned pk = sg[i];
        int vloc = (int)(pk >> 16);
        int pos = lexcl[vloc] + atomicAdd(&hist[vloc], 1);
        outbuf[pos] = (int)(pk & 0xffffu);
    }
    __syncthreads();
    for (int i = tid; i < total; i += 256) esrc[gb + i] = (unsigned short)outbuf[i];
}

// ---------------- GEMM1 via MFMA + FUSED layer-1 logits ----------------

__global__ __launch_bounds__(256) void k_gemm1m(const float* __restrict__ X, const unsigned short* __restrict__ WT,
                                                const float* __restrict__ a_src, const float* __restrict__ a_dst,
                                                unsigned char* __restrict__ H8,
                                                float* __restrict__ als, float* __restrict__ ald) {
    __shared__ unsigned short As[64][40];
    __shared__ unsigned short Bs[256][40];
    int tid = threadIdx.x;
    int row0 = blockIdx.x * 64;
    int wv = tid >> 6, lane = tid & 63;
    int wm = wv & 1, wn = wv >> 1;
    int lr = lane & 15, quad = lane >> 4;
    f32x4 acc[2][8];
#pragma unroll
    for (int mt = 0; mt < 2; ++mt)
#pragma unroll
        for (int nt = 0; nt < 8; ++nt) acc[mt][nt] = (f32x4){0.f, 0.f, 0.f, 0.f};

    int ar = tid >> 2, aseg = tid & 3;
    for (int k0 = 0; k0 < 256; k0 += 32) {
        {
            int grow = row0 + ar;
            float4 f0 = make_float4(0.f, 0.f, 0.f, 0.f), f1 = f0;
            if (grow < N_NODES) {
                const float* src = X + (size_t)grow * 256 + k0 + aseg * 8;
                f0 = *(const float4*)src;
                f1 = *(const float4*)(src + 4);
            }
            *(uint4*)&As[ar][aseg * 8] = pack_bf16_trunc(f0, f1);
        }
#pragma unroll
        for (int pass = 0; pass < 4; ++pass) {
            int q = tid + pass * 256;
            int n = q >> 2, seg = q & 3;
            uint4 v = *(const uint4*)(WT + (n << 8) + k0 + seg * 8);
            *(uint4*)&Bs[n][seg * 8] = v;
        }
        __syncthreads();
        s16x8 a[2], b[8];
#pragma unroll
        for (int mt = 0; mt < 2; ++mt) a[mt] = *(const s16x8*)&As[wm * 32 + mt * 16 + lr][quad * 8];
#pragma unroll
        for (int nt = 0; nt < 8; ++nt) b[nt] = *(const s16x8*)&Bs[wn * 128 + nt * 16 + lr][quad * 8];
#pragma unroll
        for (int mt = 0; mt < 2; ++mt)
#pragma unroll
            for (int nt = 0; nt < 8; ++nt)
                acc[mt][nt] = __builtin_amdgcn_mfma_f32_16x16x32_bf16(a[mt], b[nt], acc[mt][nt], 0, 0, 0);
        __syncthreads();
    }
#pragma unroll
    for (int mt = 0; mt < 2; ++mt) {
#pragma unroll
        for (int r = 0; r < 4; ++r) {
            int row = row0 + wm * 32 + mt * 16 + quad * 4 + r;
            if (row < N_NODES) {
#pragma unroll
                for (int nt = 0; nt < 8; ++nt) {
                    int col = wn * 128 + nt * 16 + lr;
                    H8[(size_t)row * 256 + col] = f2fp8(acc[mt][nt][r]);
                }
            }
        }
    }
    float av[8], dv[8];
#pragma unroll
    for (int nt = 0; nt < 8; ++nt) {
        int col = wn * 128 + nt * 16 + lr;
        av[nt] = a_src[col];
        dv[nt] = a_dst[col];
    }
    float ps[2][8], pd[2][8];
#pragma unroll
    for (int hl = 0; hl < 2; ++hl)
#pragma unroll
        for (int i = 0; i < 8; ++i) { ps[hl][i] = 0.f; pd[hl][i] = 0.f; }
#pragma unroll
    for (int mt = 0; mt < 2; ++mt)
#pragma unroll
        for (int nt = 0; nt < 8; ++nt) {
            int hl = nt >> 2;
#pragma unroll
            for (int r = 0; r < 4; ++r) {
                float v = acc[mt][nt][r];
                ps[hl][mt * 4 + r] = fmaf(v, av[nt], ps[hl][mt * 4 + r]);
                pd[hl][mt * 4 + r] = fmaf(v, dv[nt], pd[hl][mt * 4 + r]);
            }
        }
#pragma unroll
    for (int hl = 0; hl < 2; ++hl)
#pragma unroll
        for (int i = 0; i < 8; ++i) {
            float s = ps[hl][i], d = pd[hl][i];
#pragma unroll
            for (int m = 8; m >= 1; m >>= 1) { s += __shfl_xor(s, m); d += __shfl_xor(d, m); }
            if (lr == 0) {
                int row = row0 + wm * 32 + (i >> 2) * 16 + quad * 4 + (i & 3);
                if (row < N_NODES) {
                    als[row * 4 + wn * 2 + hl] = s;
                    ald[row * 4 + wn * 2 + hl] = d;
                }
            }
        }
}

// ---------------- edge-weight precompute, layer 1: pw1[p*4+h] = f16 exp(leaky(als[u]+ald[v])) ----------------
// node-parallel: thread = (node, head); ald in register; als gather 16B/edge; coalesced-ish writes.

__global__ __launch_bounds__(256) void k_ew1(const unsigned short* __restrict__ esrc, const int* __restrict__ off,
                                             const float* __restrict__ als1, const float* __restrict__ ald1,
                                             unsigned short* __restrict__ pw1) {
    int v = ((blockIdx.x * 256 + threadIdx.x) >> 2);
    if (v >= N_NODES) return;
    int h = threadIdx.x & 3;
    float ad = ald1[v * 4 + h];
    int p0 = off[v], p1 = off[v + 1];
    for (int p = p0; p < p1; ++p) {
        int u = esrc[p];
        float e = als1[u * 4 + h] + ad;
        e = fmaxf(e, NEG_SLOPE * e);
        pw1[p * 4 + h] = f2h(__expf(e));
    }
}

// ---------------- edge-weight precompute, layer 2: pw2[p] ----------------

__global__ __launch_bounds__(256) void k_ew2(const unsigned short* __restrict__ esrc, const int* __restrict__ off,
                                             const float* __restrict__ als2, const float* __restrict__ ald2,
                                             unsigned short* __restrict__ pw2) {
    int v = blockIdx.x * 256 + threadIdx.x;
    if (v >= N_NODES) return;
    float ad = ald2[v];
    int p0 = off[v], p1 = off[v + 1];
    for (int p = p0; p < p1; ++p) {
        float e = als2[esrc[p]] + ad;
        e = fmaxf(e, NEG_SLOPE * e);
        pw2[p] = f2h(__expf(e));
    }
}

// ---------------- Layer-1 aggregation: wave-per-node, slim loop (pw precomputed) ----------------

__global__ __launch_bounds__(256) void k_agg1(const unsigned* __restrict__ H8u,
                                              const unsigned short* __restrict__ pw1,
                                              const int* __restrict__ off, const unsigned short* __restrict__ esrc,
                                              const float* __restrict__ b1, unsigned* __restrict__ H2p) {
    int wid = (blockIdx.x * 256 + threadIdx.x) >> 6;   // grid = N/4 -> wid < N
    int lane = threadIdx.x & 63;
    int head = lane >> 4;
    int pstart = off[wid], pend = off[wid + 1];
    float l = 0.f, ax = 0.f, ay = 0.f, az = 0.f, aw = 0.f;

    auto edge1 = [&](int u0, int p) {
        unsigned v0 = H8u[(unsigned)u0 * 64 + lane];
        float pw0 = h2f(pw1[p * 4 + head]);
        l += pw0;
        f32x2 a0 = __builtin_amdgcn_cvt_pk_f32_fp8(v0, false), b0 = __builtin_amdgcn_cvt_pk_f32_fp8(v0, true);
        ax = fmaf(pw0, a0.x, ax);
        ay = fmaf(pw0, a0.y, ay);
        az = fmaf(pw0, b0.x, az);
        aw = fmaf(pw0, b0.y, aw);
    };

    int p = pstart;
    int npeel = (8 - (p & 7)) & 7;
    for (int i = 0; i < npeel && p < pend; ++i, ++p) edge1(esrc[p], p);
    for (; p + 7 < pend; p += 8) {
        uint4 ue = *(const uint4*)(esrc + p);
        unsigned u0 = ue.x & 0xffffu, u1 = ue.x >> 16, u2 = ue.y & 0xffffu, u3 = ue.y >> 16;
        unsigned u4 = ue.z & 0xffffu, u5 = ue.z >> 16, u6 = ue.w & 0xffffu, u7 = ue.w >> 16;
        unsigned v0 = H8u[u0 * 64 + lane];
        unsigned v1 = H8u[u1 * 64 + lane];
        unsigned v2 = H8u[u2 * 64 + lane];
        unsigned v3 = H8u[u3 * 64 + lane];
        unsigned v4 = H8u[u4 * 64 + lane];
        unsigned v5 = H8u[u5 * 64 + lane];
        unsigned v6 = H8u[u6 * 64 + lane];
        unsigned v7 = H8u[u7 * 64 + lane];
        float pw0 = h2f(pw1[(p + 0) * 4 + head]);
        float pw1v = h2f(pw1[(p + 1) * 4 + head]);
        float pw2v = h2f(pw1[(p + 2) * 4 + head]);
        float pw3v = h2f(pw1[(p + 3) * 4 + head]);
        float pw4v = h2f(pw1[(p + 4) * 4 + head]);
        float pw5v = h2f(pw1[(p + 5) * 4 + head]);
        float pw6v = h2f(pw1[(p + 6) * 4 + head]);
        float pw7v = h2f(pw1[(p + 7) * 4 + head]);
        l += ((pw0 + pw1v) + (pw2v + pw3v)) + ((pw4v + pw5v) + (pw6v + pw7v));
        f32x2 a0 = __builtin_amdgcn_cvt_pk_f32_fp8(v0, false), b0 = __builtin_amdgcn_cvt_pk_f32_fp8(v0, true);
        f32x2 a1 = __builtin_amdgcn_cvt_pk_f32_fp8(v1, false), b1v = __builtin_amdgcn_cvt_pk_f32_fp8(v1, true);
        f32x2 a2 = __builtin_amdgcn_cvt_pk_f32_fp8(v2, false), b2v = __builtin_amdgcn_cvt_pk_f32_fp8(v2, true);
        f32x2 a3 = __builtin_amdgcn_cvt_pk_f32_fp8(v3, false), b3v = __builtin_amdgcn_cvt_pk_f32_fp8(v3, true);
        f32x2 a4 = __builtin_amdgcn_cvt_pk_f32_fp8(v4, false), b4v = __builtin_amdgcn_cvt_pk_f32_fp8(v4, true);
        f32x2 a5 = __builtin_amdgcn_cvt_pk_f32_fp8(v5, false), b5v = __builtin_amdgcn_cvt_pk_f32_fp8(v5, true);
        f32x2 a6 = __builtin_amdgcn_cvt_pk_f32_fp8(v6, false), b6v = __builtin_amdgcn_cvt_pk_f32_fp8(v6, true);
        f32x2 a7 = __builtin_amdgcn_cvt_pk_f32_fp8(v7, false), b7v = __builtin_amdgcn_cvt_pk_f32_fp8(v7, true);
        ax = fmaf(pw3v, a3.x, fmaf(pw2v, a2.x, fmaf(pw1v, a1.x, fmaf(pw0, a0.x, ax))));
        ay = fmaf(pw3v, a3.y, fmaf(pw2v, a2.y, fmaf(pw1v, a1.y, fmaf(pw0, a0.y, ay))));
        az = fmaf(pw3v, b3v.x, fmaf(pw2v, b2v.x, fmaf(pw1v, b1v.x, fmaf(pw0, b0.x, az))));
        aw = fmaf(pw3v, b3v.y, fmaf(pw2v, b2v.y, fmaf(pw1v, b1v.y, fmaf(pw0, b0.y, aw))));
        ax = fmaf(pw7v, a7.x, fmaf(pw6v, a6.x, fmaf(pw5v, a5.x, fmaf(pw4v, a4.x, ax))));
        ay = fmaf(pw7v, a7.y, fmaf(pw6v, a6.y, fmaf(pw5v, a5.y, fmaf(pw4v, a4.y, ay))));
        az = fmaf(pw7v, b7v.x, fmaf(pw6v, b6v.x, fmaf(pw5v, b5v.x, fmaf(pw4v, b4v.x, az))));
        aw = fmaf(pw7v, b7v.y, fmaf(pw6v, b6v.y, fmaf(pw5v, b5v.y, fmaf(pw4v, b4v.y, aw))));
    }
    for (; p < pend; ++p) edge1(esrc[p], p);

    float inv = 1.f / l;
    int c = lane * 4;
    float4 bb = *(const float4*)(b1 + c);
    float o0 = ax * inv + bb.x, o1 = ay * inv + bb.y, o2 = az * inv + bb.z, o3 = aw * inv + bb.w;
    o0 = o0 > 0.f ? o0 : expm1f(o0);
    o1 = o1 > 0.f ? o1 : expm1f(o1);
    o2 = o2 > 0.f ? o2 : expm1f(o2);
    o3 = o3 > 0.f ? o3 : expm1f(o3);
    unsigned pk = __builtin_amdgcn_cvt_pk_fp8_f32(o0, o1, 0, false);
    pk = __builtin_amdgcn_cvt_pk_fp8_f32(o2, o3, pk, true);
    H2p[(unsigned)wid * 64 + lane] = pk;
}

// ---------------- GEMM2 via MFMA: g = h2(fp8->bf16) @ W2(bf16) + layer-2 logits ----------------

__global__ __launch_bounds__(256) void k_gemm2m(const unsigned* __restrict__ H2p,
                                                const unsigned short* __restrict__ W2T,
                                                const float* __restrict__ as2, const float* __restrict__ ad2,
                                                unsigned short* __restrict__ Gb, float* __restrict__ als2,
                                                float* __restrict__ ald2) {
    int tid = threadIdx.x;
    int wv = tid >> 6, lane = tid & 63, lr = lane & 15, quad = lane >> 4;
    int row0 = blockIdx.x * 64 + wv * 16;
    int rowA = row0 + lr;
    unsigned rA = (rowA < N_NODES) ? (unsigned)rowA : (unsigned)(N_NODES - 1);
    f32x4 acc[2];
    acc[0] = (f32x4){0.f, 0.f, 0.f, 0.f};
    acc[1] = (f32x4){0.f, 0.f, 0.f, 0.f};
#pragma unroll
    for (int k0 = 0; k0 < 256; k0 += 32) {
        uint2 d = *(const uint2*)(H2p + rA * 64 + (k0 >> 2) + quad * 2);
        f32x2 f0 = __builtin_amdgcn_cvt_pk_f32_fp8(d.x, false);
        f32x2 f1 = __builtin_amdgcn_cvt_pk_f32_fp8(d.x, true);
        f32x2 f2 = __builtin_amdgcn_cvt_pk_f32_fp8(d.y, false);
        f32x2 f3 = __builtin_amdgcn_cvt_pk_f32_fp8(d.y, true);
        union { uint4 u; s16x8 s; } cv;
        cv.u = pack_bf16_trunc(make_float4(f0.x, f0.y, f1.x, f1.y), make_float4(f2.x, f2.y, f3.x, f3.y));
        s16x8 afrag = cv.s;
        s16x8 b0 = *(const s16x8*)(W2T + lr * 256 + k0 + quad * 8);
        s16x8 b1f = *(const s16x8*)(W2T + (16 + lr) * 256 + k0 + quad * 8);
        acc[0] = __builtin_amdgcn_mfma_f32_16x16x32_bf16(afrag, b0, acc[0], 0, 0, 0);
        acc[1] = __builtin_amdgcn_mfma_f32_16x16x32_bf16(afrag, b1f, acc[1], 0, 0, 0);
    }
    float a2s = as2[lr], a2s2 = as2[16 + lr];
    float a2d = ad2[lr], a2d2 = ad2[16 + lr];
#pragma unroll
    for (int r = 0; r < 4; ++r) {
        int row = row0 + quad * 4 + r;
        float g0 = acc[0][r], g1 = acc[1][r];
        float s = g0 * a2s + g1 * a2s2;
        float dd = g0 * a2d + g1 * a2d2;
#pragma unroll
        for (int m = 8; m >= 1; m >>= 1) { s += __shfl_xor(s, m); dd += __shfl_xor(dd, m); }
        if (row < N_NODES) {
            Gb[(size_t)row * 32 + lr] = f2bf(g0);
            Gb[(size_t)row * 32 + 16 + lr] = f2bf(g1);
            if (lr == 0) { als2[row] = s; ald2[row] = dd; }
        }
    }
}

// ---------------- Layer-2 aggregation + bias + log_softmax (slim loop, pw precomputed) ----------------

__global__ __launch_bounds__(256) void k_agg2(const unsigned short* __restrict__ Gb,
                                              const unsigned short* __restrict__ pw2,
                                              const int* __restrict__ off, const unsigned short* __restrict__ esrc,
                                              const float* __restrict__ b2, float* __restrict__ out) {
    int gid = blockIdx.x * 256 + threadIdx.x;
    int node = gid >> 5;
    int col = gid & 31;
    if (node >= N_NODES) return;
    int pstart = off[node], pend = off[node + 1];
    float l = 0.f, acc = 0.f;

    auto edge1 = [&](int u0, int p) {
        float g0 = bf2f(Gb[(size_t)(unsigned)u0 * 32 + col]);
        float pw0 = h2f(pw2[p]);
        l += pw0;
        acc = fmaf(pw0, g0, acc);
    };

    int p = pstart;
    int npeel = (8 - (p & 7)) & 7;
    for (int i = 0; i < npeel && p < pend; ++i, ++p) edge1(esrc[p], p);
    for (; p + 7 < pend; p += 8) {
        uint4 ue = *(const uint4*)(esrc + p);
        unsigned u0 = ue.x & 0xffffu, u1 = ue.x >> 16, u2 = ue.y & 0xffffu, u3 = ue.y >> 16;
        unsigned u4 = ue.z & 0xffffu, u5 = ue.z >> 16, u6 = ue.w & 0xffffu, u7 = ue.w >> 16;
        float g0 = bf2f(Gb[(size_t)u0 * 32 + col]);
        float g1 = bf2f(Gb[(size_t)u1 * 32 + col]);
        float g2 = bf2f(Gb[(size_t)u2 * 32 + col]);
        float g3 = bf2f(Gb[(size_t)u3 * 32 + col]);
        float g4 = bf2f(Gb[(size_t)u4 * 32 + col]);
        float g5 = bf2f(Gb[(size_t)u5 * 32 + col]);
        float g6 = bf2f(Gb[(size_t)u6 * 32 + col]);
        float g7 = bf2f(Gb[(size_t)u7 * 32 + col]);
        uint4 pv = *(const uint4*)(pw2 + p);
        float pw0 = h2f((unsigned short)(pv.x & 0xffffu)), pw1v = h2f((unsigned short)(pv.x >> 16));
        float pw2v = h2f((unsigned short)(pv.y & 0xffffu)), pw3v = h2f((unsigned short)(pv.y >> 16));
        float pw4v = h2f((unsigned short)(pv.z & 0xffffu)), pw5v = h2f((unsigned short)(pv.z >> 16));
        float pw6v = h2f((unsigned short)(pv.w & 0xffffu)), pw7v = h2f((unsigned short)(pv.w >> 16));
        l += ((pw0 + pw1v) + (pw2v + pw3v)) + ((pw4v + pw5v) + (pw6v + pw7v));
        acc = fmaf(pw3v, g3, fmaf(pw2v, g2, fmaf(pw1v, g1, fmaf(pw0, g0, acc))));
        acc = fmaf(pw7v, g7, fmaf(pw6v, g6, fmaf(pw5v, g5, fmaf(pw4v, g4, acc))));
    }
    for (; p < pend; ++p) edge1(esrc[p], p);

    float o = acc / l + b2[col];
    float mm = o;
#pragma unroll
    for (int msk = 16; msk >= 1; msk >>= 1) mm = fmaxf(mm, __shfl_xor(mm, msk));
    float ex = __expf(o - mm);
    float s = ex;
#pragma unroll
    for (int msk = 16; msk >= 1; msk >>= 1) s += __shfl_xor(s, msk);
    out[(size_t)node * 32 + col] = o - mm - logf(s);
}

// ---------------- launch ----------------

extern "C" void kernel_launch(void* const* d_in, const int* in_sizes, int n_in,
                              void* d_out, int out_size, void* d_ws, size_t ws_size,
                              hipStream_t stream) {
    const float* x   = (const float*)d_in[0];
    const int*   ei  = (const int*)d_in[1];
    const float* W1  = (const float*)d_in[2];
    const float* as1 = (const float*)d_in[3];
    const float* ad1 = (const float*)d_in[4];
    const float* b1  = (const float*)d_in[5];
    const float* W2  = (const float*)d_in[6];
    const float* as2 = (const float*)d_in[7];
    const float* ad2 = (const float*)d_in[8];
    const float* b2  = (const float*)d_in[9];
    float* out = (float*)d_out;

    char* p = (char*)d_ws;
    auto alloc = [&](size_t bytes) {
        char* r = p;
        p += (bytes + 255) & ~(size_t)255;
        return r;
    };
    // workspace ~37 MB total (g/pw2/stage alias h8's region across disjoint lifetimes)
    unsigned char*  h8  = (unsigned char*)alloc((size_t)N_NODES * 256);       // 12.8 MB fp8 h1
    unsigned*       h2p = (unsigned*)alloc((size_t)N_NODES * 64 * 4);         // 12.8 MB fp8 h2 packed
    unsigned short* wt  = (unsigned short*)alloc((size_t)256 * 256 * 2);      // 128 KB bf16 W1^T
    unsigned short* w2t = (unsigned short*)alloc((size_t)32 * 256 * 2);       // 16 KB bf16 W2^T
    float* als1 = (float*)alloc((size_t)N_NODES * 4 * 4);
    float* ald1 = (float*)alloc((size_t)N_NODES * 4 * 4);
    float* als2 = (float*)alloc((size_t)N_NODES * 4);
    float* ald2 = (float*)alloc((size_t)N_NODES * 4);
    int* bcur    = (int*)alloc(256 * 4);
    int* bukbase = (int*)alloc(256 * 4);
    int* off  = (int*)alloc((size_t)(N_NODES + 1) * 4);
    unsigned short* esrc = (unsigned short*)alloc((size_t)ET * 2);            // 1.7 MB u16
    unsigned short* pw1  = (unsigned short*)alloc((size_t)ET * 4 * 2);        // 6.8 MB f16 layer-1 edge weights

    // aliases into h8's 12.8 MB (h8 live only gemm1->agg1):
    unsigned* stage = (unsigned*)h8;                            // 3.6 MB, dead before gemm1 writes h8
    unsigned short* g   = (unsigned short*)h8;                  // 3.2 MB bf16, written by gemm2 (h8 dead)
    unsigned short* pw2 = (unsigned short*)(h8 + (size_t)4 * 1024 * 1024);  // 1.7 MB f16, written by ew2

    k_cvtw<<<289, 256, 0, stream>>>(W1, W2, wt, w2t, bcur);                   // zeroes bcur
    k_bin<<<(N_EDGES + ACHUNK - 1) / ACHUNK, 256, 0, stream>>>(ei, bcur, stage);
    k_bukscan<<<1, 256, 0, stream>>>(bcur, bukbase, off);
    k_build<<<NBUK, 256, 0, stream>>>(stage, bcur, bukbase, off, esrc);

    k_gemm1m<<<(N_NODES + 63) / 64, 256, 0, stream>>>(x, wt, as1, ad1, h8, als1, ald1);
    k_ew1<<<(N_NODES * 4 + 255) / 256, 256, 0, stream>>>(esrc, off, als1, ald1, pw1);
    k_agg1<<<N_NODES / 4, 256, 0, stream>>>((const unsigned*)h8, pw1, off, esrc, b1, h2p);
    k_gemm2m<<<(N_NODES + 63) / 64, 256, 0, stream>>>(h2p, w2t, as2, ad2, g, als2, ald2);
    k_ew2<<<(N_NODES + 255) / 256, 256, 0, stream>>>(esrc, off, als2, ald2, pw2);
    k_agg2<<<(N_NODES * 32 + 255) / 256, 256, 0, stream>>>(g, pw2, off, esrc, b2, out);
}

// Round 6
// 267.558 us; speedup vs baseline: 1.0604x; 1.0604x over previous
//
#include <hip/hip_runtime.h>
#include <hip/hip_fp16.h>
#include <math.h>

#define N_NODES 50000
#define N_EDGES 800000
#define ET (N_EDGES + N_NODES)   // edges + self loops; 850000 % 8 == 0
#define NEG_SLOPE 0.2f

// binned scatter params: 256-node buckets
#define BSHIFT 8
#define NBUK ((N_NODES + 255) >> BSHIFT)    // 196 buckets
#define BCAP 4608                           // per-bucket capacity (mean 4096, +8 sigma)
#define ACHUNK 4096                         // edges per k_bin block

typedef __attribute__((ext_vector_type(8))) short s16x8;
typedef __attribute__((ext_vector_type(4))) float f32x4;
typedef __attribute__((ext_vector_type(2))) float f32x2;

__device__ __forceinline__ unsigned short f2bf(float f) {
    union { float f; unsigned u; } v; v.f = f;
    unsigned r = v.u + 0x7FFF + ((v.u >> 16) & 1);  // RNE
    return (unsigned short)(r >> 16);
}
__device__ __forceinline__ float bf2f(unsigned short s) {
    union { unsigned u; float f; } v; v.u = ((unsigned)s) << 16;
    return v.f;
}
__device__ __forceinline__ unsigned short f2h(float f) {
    union { _Float16 h; unsigned short s; } v; v.h = (_Float16)f; return v.s;
}
__device__ __forceinline__ float h2f(unsigned short s) {
    union { unsigned short s; _Float16 h; } v; v.s = s; return (float)v.h;
}
// truncation-pack 8 fp32 -> 8 bf16
__device__ __forceinline__ uint4 pack_bf16_trunc(float4 f0, float4 f1) {
    const unsigned* a = (const unsigned*)&f0;
    const unsigned* b = (const unsigned*)&f1;
    uint4 r;
    r.x = (a[0] >> 16) | (a[1] & 0xffff0000u);
    r.y = (a[2] >> 16) | (a[3] & 0xffff0000u);
    r.z = (b[0] >> 16) | (b[1] & 0xffff0000u);
    r.w = (b[2] >> 16) | (b[3] & 0xffff0000u);
    return r;
}
// fp8 e4m3 (OCP) — HW convert
__device__ __forceinline__ unsigned char f2fp8(float f) {
    return (unsigned char)(__builtin_amdgcn_cvt_pk_fp8_f32(f, f, 0, false) & 0xff);
}

// ---------------- weight converts + bcur zeroing (fused; runs first) ----------------

__global__ __launch_bounds__(256) void k_cvtw(const float* __restrict__ W1, const float* __restrict__ W2,
                                              unsigned short* __restrict__ WT, unsigned short* __restrict__ W2T,
                                              int* __restrict__ bcur) {
    int b = blockIdx.x, k = threadIdx.x;
    if (b < 256) {
        WT[b * 256 + k] = f2bf(W1[k * 256 + b]);
    } else if (b < 288) {
        int c = b - 256;
        W2T[c * 256 + k] = f2bf(W2[k * 32 + c]);
    } else {
        if (k < NBUK) bcur[k] = 0;
    }
}

// ---------------- Phase A: LDS-binned edge staging ----------------

__global__ __launch_bounds__(256) void k_bin(const int* __restrict__ ei, int* __restrict__ bcur,
                                             unsigned* __restrict__ stage) {
    __shared__ unsigned sdata[ACHUNK];        // packed u | vloc<<16, bucket-major
    __shared__ unsigned short sv[ACHUNK];     // v cached between passes (v < 65536)
    __shared__ int scnt[NBUK];                // counts, then pass-2 cursors
    __shared__ int soff[NBUK + 1];            // exclusive scan
    __shared__ int sgbase[NBUK];              // global base per bucket
    __shared__ int wssc[4];
    int tid = threadIdx.x;
    int e0 = blockIdx.x * ACHUNK;
    int nE = N_EDGES - e0;
    if (nE > ACHUNK) nE = ACHUNK;
    for (int i = tid; i < NBUK; i += 256) scnt[i] = 0;
    __syncthreads();
    for (int i = tid; i < nE; i += 256) {
        int v = ei[N_EDGES + e0 + i];
        sv[i] = (unsigned short)v;
        atomicAdd(&scnt[v >> BSHIFT], 1);
    }
    __syncthreads();
    {
        int lane = tid & 63, w = tid >> 6;
        int val = (tid < NBUK) ? scnt[tid] : 0;
        int incl = val;
        for (int o = 1; o < 64; o <<= 1) {
            int t = __shfl_up(incl, o);
            if (lane >= o) incl += t;
        }
        if (lane == 63) wssc[w] = incl;
        __syncthreads();
        int wb = 0;
        for (int i = 0; i < w; ++i) wb += wssc[i];
        if (tid < NBUK) soff[tid] = wb + incl - val;
        if (tid == 255) soff[NBUK] = wb + incl;
    }
    __syncthreads();
    if (tid < NBUK) {
        int c = scnt[tid];
        sgbase[tid] = c ? atomicAdd(&bcur[tid], c) : 0;
        scnt[tid] = soff[tid];
    }
    __syncthreads();
    for (int i = tid; i < nE; i += 256) {
        int u = ei[e0 + i];
        unsigned v = sv[i];
        int b = (int)(v >> BSHIFT);
        int pos = atomicAdd(&scnt[b], 1);
        sdata[pos] = (unsigned)u | ((v & 255u) << 16);
    }
    __syncthreads();
    for (int i = tid; i < nE; i += 256) {
        int lo = 0, hi = NBUK - 1;
        while (lo < hi) {
            int mid = (lo + hi + 1) >> 1;
            if (soff[mid] <= i) lo = mid; else hi = mid - 1;
        }
        int rel = sgbase[lo] + (i - soff[lo]);
        if (rel < BCAP) stage[(size_t)lo * BCAP + rel] = sdata[i];
    }
}

// ---------------- bucket-base scan (1 block; also writes off[N]) ----------------

__global__ __launch_bounds__(256) void k_bukscan(const int* __restrict__ bcur, int* __restrict__ bukbase,
                                                 int* __restrict__ off) {
    __shared__ int ws[4];
    int tid = threadIdx.x, lane = tid & 63, w = tid >> 6;
    int val = 0;
    if (tid < NBUK) {
        int base = tid << BSHIFT;
        int nv = N_NODES - base;
        if (nv > 256) nv = 256;
        val = bcur[tid] + nv;   // edges + self-loops in this bucket
    }
    int incl = val;
    for (int o = 1; o < 64; o <<= 1) {
        int t = __shfl_up(incl, o);
        if (lane >= o) incl += t;
    }
    if (lane == 63) ws[w] = incl;
    __syncthreads();
    int wb = 0;
    for (int i = 0; i < w; ++i) wb += ws[i];
    if (tid < NBUK) bukbase[tid] = wb + incl - val;
    if (tid == 0) off[N_NODES] = ET;
}

// ---------------- Phase B: per-bucket CSR build (esrc + edst as u16) ----------------

__global__ __launch_bounds__(256) void k_build(const unsigned* __restrict__ stage,
                                               const int* __restrict__ bcur, const int* __restrict__ bukbase,
                                               int* __restrict__ off, unsigned short* __restrict__ esrc,
                                               unsigned short* __restrict__ edst) {
    __shared__ int hist[256];            // counts, then per-node cursors
    __shared__ int lexcl[257];
    __shared__ int ws[4];
    __shared__ unsigned outbuf[BCAP + 256];   // packed u | vloc<<16
    int b = blockIdx.x, tid = threadIdx.x;
    int n = bcur[b];
    if (n > BCAP) n = BCAP;
    int base = b << BSHIFT;
    int nv = N_NODES - base;
    if (nv > 256) nv = 256;
    hist[tid] = 0;
    __syncthreads();
    const unsigned* sg = stage + (size_t)b * BCAP;
    for (int i = tid; i < n; i += 256) atomicAdd(&hist[sg[i] >> 16], 1);
    __syncthreads();
    int lane = tid & 63, w = tid >> 6;
    int val = (tid < nv) ? hist[tid] + 1 : 0;
    int incl = val;
    for (int o = 1; o < 64; o <<= 1) {
        int t = __shfl_up(incl, o);
        if (lane >= o) incl += t;
    }
    if (lane == 63) ws[w] = incl;
    __syncthreads();
    int wb = 0;
    for (int i = 0; i < w; ++i) wb += ws[i];
    int excl = wb + incl - val;
    lexcl[tid] = excl;
    if (tid == 255) lexcl[256] = excl + val;   // total = n + nv
    int gb = bukbase[b];
    if (tid < nv) off[base + tid] = gb + excl;
    __syncthreads();
    int total = lexcl[256];
    if (tid < nv) {
        outbuf[excl] = (unsigned)(base + tid) | ((unsigned)tid << 16);   // self-loop first
        hist[tid] = 1;
    }
    __syncthreads();
    for (int i = tid; i < n; i += 256) {
        unsigned pk = sg[i];
        int vloc = (int)(pk >> 16);
        int pos = lexcl[vloc] + atomicAdd(&hist[vloc], 1);
        outbuf[pos] = pk;
    }
    __syncthreads();
    for (int i = tid; i < total; i += 256) {
        unsigned pk = outbuf[i];
        esrc[gb + i] = (unsigned short)(pk & 0xffffu);
        edst[gb + i] = (unsigned short)(base + (int)(pk >> 16));
    }
}

// ---------------- GEMM1 via MFMA + FUSED layer-1 logits ----------------

__global__ __launch_bounds__(256) void k_gemm1m(const float* __restrict__ X, const unsigned short* __restrict__ WT,
                                                const float* __restrict__ a_src, const float* __restrict__ a_dst,
                                                unsigned char* __restrict__ H8,
                                                float* __restrict__ als, float* __restrict__ ald) {
    __shared__ unsigned short As[64][40];
    __shared__ unsigned short Bs[256][40];
    int tid = threadIdx.x;
    int row0 = blockIdx.x * 64;
    int wv = tid >> 6, lane = tid & 63;
    int wm = wv & 1, wn = wv >> 1;
    int lr = lane & 15, quad = lane >> 4;
    f32x4 acc[2][8];
#pragma unroll
    for (int mt = 0; mt < 2; ++mt)
#pragma unroll
        for (int nt = 0; nt < 8; ++nt) acc[mt][nt] = (f32x4){0.f, 0.f, 0.f, 0.f};

    int ar = tid >> 2, aseg = tid & 3;
    for (int k0 = 0; k0 < 256; k0 += 32) {
        {
            int grow = row0 + ar;
            float4 f0 = make_float4(0.f, 0.f, 0.f, 0.f), f1 = f0;
            if (grow < N_NODES) {
                const float* src = X + (size_t)grow * 256 + k0 + aseg * 8;
                f0 = *(const float4*)src;
                f1 = *(const float4*)(src + 4);
            }
            *(uint4*)&As[ar][aseg * 8] = pack_bf16_trunc(f0, f1);
        }
#pragma unroll
        for (int pass = 0; pass < 4; ++pass) {
            int q = tid + pass * 256;
            int n = q >> 2, seg = q & 3;
            uint4 v = *(const uint4*)(WT + (n << 8) + k0 + seg * 8);
            *(uint4*)&Bs[n][seg * 8] = v;
        }
        __syncthreads();
        s16x8 a[2], b[8];
#pragma unroll
        for (int mt = 0; mt < 2; ++mt) a[mt] = *(const s16x8*)&As[wm * 32 + mt * 16 + lr][quad * 8];
#pragma unroll
        for (int nt = 0; nt < 8; ++nt) b[nt] = *(const s16x8*)&Bs[wn * 128 + nt * 16 + lr][quad * 8];
#pragma unroll
        for (int mt = 0; mt < 2; ++mt)
#pragma unroll
            for (int nt = 0; nt < 8; ++nt)
                acc[mt][nt] = __builtin_amdgcn_mfma_f32_16x16x32_bf16(a[mt], b[nt], acc[mt][nt], 0, 0, 0);
        __syncthreads();
    }
#pragma unroll
    for (int mt = 0; mt < 2; ++mt) {
#pragma unroll
        for (int r = 0; r < 4; ++r) {
            int row = row0 + wm * 32 + mt * 16 + quad * 4 + r;
            if (row < N_NODES) {
#pragma unroll
                for (int nt = 0; nt < 8; ++nt) {
                    int col = wn * 128 + nt * 16 + lr;
                    H8[(size_t)row * 256 + col] = f2fp8(acc[mt][nt][r]);
                }
            }
        }
    }
    float av[8], dv[8];
#pragma unroll
    for (int nt = 0; nt < 8; ++nt) {
        int col = wn * 128 + nt * 16 + lr;
        av[nt] = a_src[col];
        dv[nt] = a_dst[col];
    }
    float ps[2][8], pd[2][8];
#pragma unroll
    for (int hl = 0; hl < 2; ++hl)
#pragma unroll
        for (int i = 0; i < 8; ++i) { ps[hl][i] = 0.f; pd[hl][i] = 0.f; }
#pragma unroll
    for (int mt = 0; mt < 2; ++mt)
#pragma unroll
        for (int nt = 0; nt < 8; ++nt) {
            int hl = nt >> 2;
#pragma unroll
            for (int r = 0; r < 4; ++r) {
                float v = acc[mt][nt][r];
                ps[hl][mt * 4 + r] = fmaf(v, av[nt], ps[hl][mt * 4 + r]);
                pd[hl][mt * 4 + r] = fmaf(v, dv[nt], pd[hl][mt * 4 + r]);
            }
        }
#pragma unroll
    for (int hl = 0; hl < 2; ++hl)
#pragma unroll
        for (int i = 0; i < 8; ++i) {
            float s = ps[hl][i], d = pd[hl][i];
#pragma unroll
            for (int m = 8; m >= 1; m >>= 1) { s += __shfl_xor(s, m); d += __shfl_xor(d, m); }
            if (lr == 0) {
                int row = row0 + wm * 32 + (i >> 2) * 16 + quad * 4 + (i & 3);
                if (row < N_NODES) {
                    als[row * 4 + wn * 2 + hl] = s;
                    ald[row * 4 + wn * 2 + hl] = d;
                }
            }
        }
}

// ---------------- edge-weight precompute, layer 1 (EDGE-parallel, head-major planes) ----------------
// thread = edge; reads als1[u] (L2-resident 800KB) + ald1[v] (v sorted -> sequential);
// writes pw1h[h*ET + p] f16 — 4 perfectly coalesced streams, no write amplification.

__global__ __launch_bounds__(256) void k_ew1e(const unsigned short* __restrict__ esrc,
                                              const unsigned short* __restrict__ edst,
                                              const float* __restrict__ als1, const float* __restrict__ ald1,
                                              unsigned short* __restrict__ pw1h) {
    int p = blockIdx.x * 256 + threadIdx.x;
    if (p >= ET) return;
    int u = esrc[p], v = edst[p];
    float4 s = *(const float4*)(als1 + (size_t)u * 4);
    float4 d = *(const float4*)(ald1 + (size_t)v * 4);
    float e0 = s.x + d.x, e1 = s.y + d.y, e2 = s.z + d.z, e3 = s.w + d.w;
    e0 = fmaxf(e0, NEG_SLOPE * e0);
    e1 = fmaxf(e1, NEG_SLOPE * e1);
    e2 = fmaxf(e2, NEG_SLOPE * e2);
    e3 = fmaxf(e3, NEG_SLOPE * e3);
    pw1h[p]          = f2h(__expf(e0));
    pw1h[ET + p]     = f2h(__expf(e1));
    pw1h[2 * ET + p] = f2h(__expf(e2));
    pw1h[3 * ET + p] = f2h(__expf(e3));
}

// ---------------- Layer-1 aggregation: wave-per-node, slim loop (pw precomputed, vectorized) ----------------

__global__ __launch_bounds__(256) void k_agg1(const unsigned* __restrict__ H8u,
                                              const unsigned short* __restrict__ pw1h,
                                              const int* __restrict__ off, const unsigned short* __restrict__ esrc,
                                              const float* __restrict__ b1, unsigned* __restrict__ H2p) {
    int wid = (blockIdx.x * 256 + threadIdx.x) >> 6;   // grid = N/4 -> wid < N
    int lane = threadIdx.x & 63;
    int head = lane >> 4;
    const unsigned short* pwh = pw1h + (size_t)head * ET;
    int pstart = off[wid], pend = off[wid + 1];
    float l = 0.f, ax = 0.f, ay = 0.f, az = 0.f, aw = 0.f;

    auto edge1 = [&](int u0, int p) {
        unsigned v0 = H8u[(unsigned)u0 * 64 + lane];
        float pw0 = h2f(pwh[p]);
        l += pw0;
        f32x2 a0 = __builtin_amdgcn_cvt_pk_f32_fp8(v0, false), b0 = __builtin_amdgcn_cvt_pk_f32_fp8(v0, true);
        ax = fmaf(pw0, a0.x, ax);
        ay = fmaf(pw0, a0.y, ay);
        az = fmaf(pw0, b0.x, az);
        aw = fmaf(pw0, b0.y, aw);
    };

    int p = pstart;
    int npeel = (8 - (p & 7)) & 7;
    for (int i = 0; i < npeel && p < pend; ++i, ++p) edge1(esrc[p], p);
    for (; p + 7 < pend; p += 8) {
        uint4 ue = *(const uint4*)(esrc + p);
        unsigned u0 = ue.x & 0xffffu, u1 = ue.x >> 16, u2 = ue.y & 0xffffu, u3 = ue.y >> 16;
        unsigned u4 = ue.z & 0xffffu, u5 = ue.z >> 16, u6 = ue.w & 0xffffu, u7 = ue.w >> 16;
        unsigned v0 = H8u[u0 * 64 + lane];
        unsigned v1 = H8u[u1 * 64 + lane];
        unsigned v2 = H8u[u2 * 64 + lane];
        unsigned v3 = H8u[u3 * 64 + lane];
        unsigned v4 = H8u[u4 * 64 + lane];
        unsigned v5 = H8u[u5 * 64 + lane];
        unsigned v6 = H8u[u6 * 64 + lane];
        unsigned v7 = H8u[u7 * 64 + lane];
        uint4 pv = *(const uint4*)(pwh + p);   // 8 f16 weights, one 16B broadcast per head-group
        float pw0 = h2f((unsigned short)(pv.x & 0xffffu)), pw1v = h2f((unsigned short)(pv.x >> 16));
        float pw2v = h2f((unsigned short)(pv.y & 0xffffu)), pw3v = h2f((unsigned short)(pv.y >> 16));
        float pw4v = h2f((unsigned short)(pv.z & 0xffffu)), pw5v = h2f((unsigned short)(pv.z >> 16));
        float pw6v = h2f((unsigned short)(pv.w & 0xffffu)), pw7v = h2f((unsigned short)(pv.w >> 16));
        l += ((pw0 + pw1v) + (pw2v + pw3v)) + ((pw4v + pw5v) + (pw6v + pw7v));
        f32x2 a0 = __builtin_amdgcn_cvt_pk_f32_fp8(v0, false), b0 = __builtin_amdgcn_cvt_pk_f32_fp8(v0, true);
        f32x2 a1 = __builtin_amdgcn_cvt_pk_f32_fp8(v1, false), b1v = __builtin_amdgcn_cvt_pk_f32_fp8(v1, true);
        f32x2 a2 = __builtin_amdgcn_cvt_pk_f32_fp8(v2, false), b2v = __builtin_amdgcn_cvt_pk_f32_fp8(v2, true);
        f32x2 a3 = __builtin_amdgcn_cvt_pk_f32_fp8(v3, false), b3v = __builtin_amdgcn_cvt_pk_f32_fp8(v3, true);
        f32x2 a4 = __builtin_amdgcn_cvt_pk_f32_fp8(v4, false), b4v = __builtin_amdgcn_cvt_pk_f32_fp8(v4, true);
        f32x2 a5 = __builtin_amdgcn_cvt_pk_f32_fp8(v5, false), b5v = __builtin_amdgcn_cvt_pk_f32_fp8(v5, true);
        f32x2 a6 = __builtin_amdgcn_cvt_pk_f32_fp8(v6, false), b6v = __builtin_amdgcn_cvt_pk_f32_fp8(v6, true);
        f32x2 a7 = __builtin_amdgcn_cvt_pk_f32_fp8(v7, false), b7v = __builtin_amdgcn_cvt_pk_f32_fp8(v7, true);
        ax = fmaf(pw3v, a3.x, fmaf(pw2v, a2.x, fmaf(pw1v, a1.x, fmaf(pw0, a0.x, ax))));
        ay = fmaf(pw3v, a3.y, fmaf(pw2v, a2.y, fmaf(pw1v, a1.y, fmaf(pw0, a0.y, ay))));
        az = fmaf(pw3v, b3v.x, fmaf(pw2v, b2v.x, fmaf(pw1v, b1v.x, fmaf(pw0, b0.x, az))));
        aw = fmaf(pw3v, b3v.y, fmaf(pw2v, b2v.y, fmaf(pw1v, b1v.y, fmaf(pw0, b0.y, aw))));
        ax = fmaf(pw7v, a7.x, fmaf(pw6v, a6.x, fmaf(pw5v, a5.x, fmaf(pw4v, a4.x, ax))));
        ay = fmaf(pw7v, a7.y, fmaf(pw6v, a6.y, fmaf(pw5v, a5.y, fmaf(pw4v, a4.y, ay))));
        az = fmaf(pw7v, b7v.x, fmaf(pw6v, b6v.x, fmaf(pw5v, b5v.x, fmaf(pw4v, b4v.x, az))));
        aw = fmaf(pw7v, b7v.y, fmaf(pw6v, b6v.y, fmaf(pw5v, b5v.y, fmaf(pw4v, b4v.y, aw))));
    }
    for (; p < pend; ++p) edge1(esrc[p], p);

    float inv = 1.f / l;
    int c = lane * 4;
    float4 bb = *(const float4*)(b1 + c);
    float o0 = ax * inv + bb.x, o1 = ay * inv + bb.y, o2 = az * inv + bb.z, o3 = aw * inv + bb.w;
    o0 = o0 > 0.f ? o0 : expm1f(o0);
    o1 = o1 > 0.f ? o1 : expm1f(o1);
    o2 = o2 > 0.f ? o2 : expm1f(o2);
    o3 = o3 > 0.f ? o3 : expm1f(o3);
    unsigned pk = __builtin_amdgcn_cvt_pk_fp8_f32(o0, o1, 0, false);
    pk = __builtin_amdgcn_cvt_pk_fp8_f32(o2, o3, pk, true);
    H2p[(unsigned)wid * 64 + lane] = pk;
}

// ---------------- GEMM2 via MFMA: g = h2(fp8->bf16) @ W2(bf16) + layer-2 logits ----------------

__global__ __launch_bounds__(256) void k_gemm2m(const unsigned* __restrict__ H2p,
                                                const unsigned short* __restrict__ W2T,
                                                const float* __restrict__ as2, const float* __restrict__ ad2,
                                                unsigned short* __restrict__ Gb, float* __restrict__ als2,
                                                float* __restrict__ ald2) {
    int tid = threadIdx.x;
    int wv = tid >> 6, lane = tid & 63, lr = lane & 15, quad = lane >> 4;
    int row0 = blockIdx.x * 64 + wv * 16;
    int rowA = row0 + lr;
    unsigned rA = (rowA < N_NODES) ? (unsigned)rowA : (unsigned)(N_NODES - 1);
    f32x4 acc[2];
    acc[0] = (f32x4){0.f, 0.f, 0.f, 0.f};
    acc[1] = (f32x4){0.f, 0.f, 0.f, 0.f};
#pragma unroll
    for (int k0 = 0; k0 < 256; k0 += 32) {
        uint2 d = *(const uint2*)(H2p + rA * 64 + (k0 >> 2) + quad * 2);
        f32x2 f0 = __builtin_amdgcn_cvt_pk_f32_fp8(d.x, false);
        f32x2 f1 = __builtin_amdgcn_cvt_pk_f32_fp8(d.x, true);
        f32x2 f2 = __builtin_amdgcn_cvt_pk_f32_fp8(d.y, false);
        f32x2 f3 = __builtin_amdgcn_cvt_pk_f32_fp8(d.y, true);
        union { uint4 u; s16x8 s; } cv;
        cv.u = pack_bf16_trunc(make_float4(f0.x, f0.y, f1.x, f1.y), make_float4(f2.x, f2.y, f3.x, f3.y));
        s16x8 afrag = cv.s;
        s16x8 b0 = *(const s16x8*)(W2T + lr * 256 + k0 + quad * 8);
        s16x8 b1f = *(const s16x8*)(W2T + (16 + lr) * 256 + k0 + quad * 8);
        acc[0] = __builtin_amdgcn_mfma_f32_16x16x32_bf16(afrag, b0, acc[0], 0, 0, 0);
        acc[1] = __builtin_amdgcn_mfma_f32_16x16x32_bf16(afrag, b1f, acc[1], 0, 0, 0);
    }
    float a2s = as2[lr], a2s2 = as2[16 + lr];
    float a2d = ad2[lr], a2d2 = ad2[16 + lr];
#pragma unroll
    for (int r = 0; r < 4; ++r) {
        int row = row0 + quad * 4 + r;
        float g0 = acc[0][r], g1 = acc[1][r];
        float s = g0 * a2s + g1 * a2s2;
        float dd = g0 * a2d + g1 * a2d2;
#pragma unroll
        for (int m = 8; m >= 1; m >>= 1) { s += __shfl_xor(s, m); dd += __shfl_xor(dd, m); }
        if (row < N_NODES) {
            Gb[(size_t)row * 32 + lr] = f2bf(g0);
            Gb[(size_t)row * 32 + 16 + lr] = f2bf(g1);
            if (lr == 0) { als2[row] = s; ald2[row] = dd; }
        }
    }
}

// ---------------- Layer-2 aggregation + bias + log_softmax (inline exp, u16 esrc) ----------------

__global__ __launch_bounds__(256) void k_agg2(const unsigned short* __restrict__ Gb,
                                              const float* __restrict__ als2,
                                              const float* __restrict__ ald2_, const int* __restrict__ off,
                                              const unsigned short* __restrict__ esrc, const float* __restrict__ b2,
                                              float* __restrict__ out) {
    int gid = blockIdx.x * 256 + threadIdx.x;
    int node = gid >> 5;
    int col = gid & 31;
    if (node >= N_NODES) return;
    float ald = ald2_[node];
    int pstart = off[node], pend = off[node + 1];
    float l = 0.f, acc = 0.f;

    auto edge1 = [&](int u0) {
        float g0 = bf2f(Gb[(size_t)(unsigned)u0 * 32 + col]);
        float e0 = als2[u0] + ald;
        e0 = fmaxf(e0, NEG_SLOPE * e0);
        float pw0 = __expf(e0);
        l += pw0;
        acc = fmaf(pw0, g0, acc);
    };

    int p = pstart;
    int npeel = (8 - (p & 7)) & 7;
    for (int i = 0; i < npeel && p < pend; ++i, ++p) edge1(esrc[p]);
    for (; p + 7 < pend; p += 8) {
        uint4 ue = *(const uint4*)(esrc + p);
        unsigned u0 = ue.x & 0xffffu, u1 = ue.x >> 16, u2 = ue.y & 0xffffu, u3 = ue.y >> 16;
        unsigned u4 = ue.z & 0xffffu, u5 = ue.z >> 16, u6 = ue.w & 0xffffu, u7 = ue.w >> 16;
        float g0 = bf2f(Gb[(size_t)u0 * 32 + col]);
        float g1 = bf2f(Gb[(size_t)u1 * 32 + col]);
        float g2 = bf2f(Gb[(size_t)u2 * 32 + col]);
        float g3 = bf2f(Gb[(size_t)u3 * 32 + col]);
        float g4 = bf2f(Gb[(size_t)u4 * 32 + col]);
        float g5 = bf2f(Gb[(size_t)u5 * 32 + col]);
        float g6 = bf2f(Gb[(size_t)u6 * 32 + col]);
        float g7 = bf2f(Gb[(size_t)u7 * 32 + col]);
        float e0 = als2[u0] + ald, e1 = als2[u1] + ald, e2 = als2[u2] + ald, e3 = als2[u3] + ald;
        float e4 = als2[u4] + ald, e5 = als2[u5] + ald, e6 = als2[u6] + ald, e7 = als2[u7] + ald;
        e0 = fmaxf(e0, NEG_SLOPE * e0); e1 = fmaxf(e1, NEG_SLOPE * e1);
        e2 = fmaxf(e2, NEG_SLOPE * e2); e3 = fmaxf(e3, NEG_SLOPE * e3);
        e4 = fmaxf(e4, NEG_SLOPE * e4); e5 = fmaxf(e5, NEG_SLOPE * e5);
        e6 = fmaxf(e6, NEG_SLOPE * e6); e7 = fmaxf(e7, NEG_SLOPE * e7);
        float pw0 = __expf(e0), pw1 = __expf(e1), pw2 = __expf(e2), pw3 = __expf(e3);
        float pw4 = __expf(e4), pw5 = __expf(e5), pw6 = __expf(e6), pw7 = __expf(e7);
        l += ((pw0 + pw1) + (pw2 + pw3)) + ((pw4 + pw5) + (pw6 + pw7));
        acc = fmaf(pw3, g3, fmaf(pw2, g2, fmaf(pw1, g1, fmaf(pw0, g0, acc))));
        acc = fmaf(pw7, g7, fmaf(pw6, g6, fmaf(pw5, g5, fmaf(pw4, g4, acc))));
    }
    for (; p < pend; ++p) edge1(esrc[p]);

    float o = acc / l + b2[col];
    float mm = o;
#pragma unroll
    for (int msk = 16; msk >= 1; msk >>= 1) mm = fmaxf(mm, __shfl_xor(mm, msk));
    float ex = __expf(o - mm);
    float s = ex;
#pragma unroll
    for (int msk = 16; msk >= 1; msk >>= 1) s += __shfl_xor(s, msk);
    out[(size_t)node * 32 + col] = o - mm - logf(s);
}

// ---------------- launch ----------------

extern "C" void kernel_launch(void* const* d_in, const int* in_sizes, int n_in,
                              void* d_out, int out_size, void* d_ws, size_t ws_size,
                              hipStream_t stream) {
    const float* x   = (const float*)d_in[0];
    const int*   ei  = (const int*)d_in[1];
    const float* W1  = (const float*)d_in[2];
    const float* as1 = (const float*)d_in[3];
    const float* ad1 = (const float*)d_in[4];
    const float* b1  = (const float*)d_in[5];
    const float* W2  = (const float*)d_in[6];
    const float* as2 = (const float*)d_in[7];
    const float* ad2 = (const float*)d_in[8];
    const float* b2  = (const float*)d_in[9];
    float* out = (float*)d_out;

    char* p = (char*)d_ws;
    auto alloc = [&](size_t bytes) {
        char* r = p;
        p += (bytes + 255) & ~(size_t)255;
        return r;
    };
    // workspace ~36.5 MB (stage+edst alias h2p; g aliases h8 — disjoint lifetimes)
    unsigned char*  h8  = (unsigned char*)alloc((size_t)N_NODES * 256);       // 12.8 MB fp8 h1
    unsigned char*  h2pr= (unsigned char*)alloc((size_t)N_NODES * 64 * 4);    // 12.8 MB fp8 h2 packed
    unsigned short* wt  = (unsigned short*)alloc((size_t)256 * 256 * 2);      // 128 KB bf16 W1^T
    unsigned short* w2t = (unsigned short*)alloc((size_t)32 * 256 * 2);       // 16 KB bf16 W2^T
    float* als1 = (float*)alloc((size_t)N_NODES * 4 * 4);
    float* ald1 = (float*)alloc((size_t)N_NODES * 4 * 4);
    float* als2 = (float*)alloc((size_t)N_NODES * 4);
    float* ald2 = (float*)alloc((size_t)N_NODES * 4);
    int* bcur    = (int*)alloc(256 * 4);
    int* bukbase = (int*)alloc(256 * 4);
    int* off  = (int*)alloc((size_t)(N_NODES + 1) * 4);
    unsigned short* esrc = (unsigned short*)alloc((size_t)ET * 2);            // 1.7 MB u16
    unsigned short* pw1h = (unsigned short*)alloc((size_t)ET * 4 * 2);        // 6.8 MB f16, head-major planes

    unsigned* h2p = (unsigned*)h2pr;
    // aliases into h2p's 12.8 MB (h2p first written by agg1, long after these are dead):
    unsigned* stage = (unsigned*)h2pr;                                        // 3.6 MB (k_bin -> k_build)
    unsigned short* edst = (unsigned short*)(h2pr + (size_t)4 * 1024 * 1024); // 1.7 MB (k_build -> k_ew1e)
    // alias into h8's 12.8 MB (h8 dead after agg1; g written by gemm2m):
    unsigned short* g = (unsigned short*)h8;                                  // 3.2 MB bf16

    k_cvtw<<<289, 256, 0, stream>>>(W1, W2, wt, w2t, bcur);                   // zeroes bcur
    k_bin<<<(N_EDGES + ACHUNK - 1) / ACHUNK, 256, 0, stream>>>(ei, bcur, stage);
    k_bukscan<<<1, 256, 0, stream>>>(bcur, bukbase, off);
    k_build<<<NBUK, 256, 0, stream>>>(stage, bcur, bukbase, off, esrc, edst);

    k_gemm1m<<<(N_NODES + 63) / 64, 256, 0, stream>>>(x, wt, as1, ad1, h8, als1, ald1);
    k_ew1e<<<(ET + 255) / 256, 256, 0, stream>>>(esrc, edst, als1, ald1, pw1h);
    k_agg1<<<N_NODES / 4, 256, 0, stream>>>((const unsigned*)h8, pw1h, off, esrc, b1, h2p);
    k_gemm2m<<<(N_NODES + 63) / 64, 256, 0, stream>>>(h2p, w2t, as2, ad2, g, als2, ald2);
    k_agg2<<<(N_NODES * 32 + 255) / 256, 256, 0, stream>>>(g, als2, ald2, off, esrc, b2, out);
}

// Round 7
// 227.103 us; speedup vs baseline: 1.2493x; 1.1781x over previous
//
#include <hip/hip_runtime.h>
#include <math.h>

#define N_NODES 50000
#define N_EDGES 800000
#define NEG_SLOPE 0.2f
#define PADU N_NODES               // pad sentinel source index (als1 row = -1e30)

// binned scatter params: 256-node buckets
#define BSHIFT 8
#define NBUK ((N_NODES + 255) >> BSHIFT)    // 196 buckets
#define BCAP 4608                           // per-bucket capacity (mean 4096, +8 sigma)
#define ACHUNK 4096                         // edges per k_bin block
#define ET_PAD_ALLOC 1000960                // >= sum of per-bucket padded reserves

typedef __attribute__((ext_vector_type(8))) short s16x8;
typedef __attribute__((ext_vector_type(4))) float f32x4;
typedef __attribute__((ext_vector_type(2))) float f32x2;

__device__ __forceinline__ unsigned short f2bf(float f) {
    union { float f; unsigned u; } v; v.f = f;
    unsigned r = v.u + 0x7FFF + ((v.u >> 16) & 1);  // RNE
    return (unsigned short)(r >> 16);
}
__device__ __forceinline__ float bf2f(unsigned short s) {
    union { unsigned u; float f; } v; v.u = ((unsigned)s) << 16;
    return v.f;
}
// truncation-pack 8 fp32 -> 8 bf16
__device__ __forceinline__ uint4 pack_bf16_trunc(float4 f0, float4 f1) {
    const unsigned* a = (const unsigned*)&f0;
    const unsigned* b = (const unsigned*)&f1;
    uint4 r;
    r.x = (a[0] >> 16) | (a[1] & 0xffff0000u);
    r.y = (a[2] >> 16) | (a[3] & 0xffff0000u);
    r.z = (b[0] >> 16) | (b[1] & 0xffff0000u);
    r.w = (b[2] >> 16) | (b[3] & 0xffff0000u);
    return r;
}
// fp8 e4m3 (OCP) — HW convert
__device__ __forceinline__ unsigned char f2fp8(float f) {
    return (unsigned char)(__builtin_amdgcn_cvt_pk_fp8_f32(f, f, 0, false) & 0xff);
}

// ---------------- weight converts + bcur zeroing + als1 pad-sentinel ----------------

__global__ __launch_bounds__(256) void k_cvtw(const float* __restrict__ W1, const float* __restrict__ W2,
                                              unsigned short* __restrict__ WT, unsigned short* __restrict__ W2T,
                                              int* __restrict__ bcur, float* __restrict__ als1) {
    int b = blockIdx.x, k = threadIdx.x;
    if (b < 256) {
        WT[b * 256 + k] = f2bf(W1[k * 256 + b]);
    } else if (b < 288) {
        int c = b - 256;
        W2T[c * 256 + k] = f2bf(W2[k * 32 + c]);
    } else {
        if (k < NBUK) bcur[k] = 0;
        if (k >= 196 && k < 200) als1[N_NODES * 4 + (k - 196)] = -1e30f;   // pad row: exp -> 0
    }
}

// ---------------- Phase A: LDS-binned edge staging (bucket id packed in bits 24-31) ----------------

__global__ __launch_bounds__(256) void k_bin(const int* __restrict__ ei, int* __restrict__ bcur,
                                             unsigned* __restrict__ stage) {
    __shared__ unsigned sdata[ACHUNK];        // u | vloc<<16 | buk<<24, bucket-major
    __shared__ unsigned short sv[ACHUNK];     // v cached between passes (v < 65536)
    __shared__ int scnt[NBUK];                // counts, then pass-2 cursors
    __shared__ int soff[NBUK + 1];            // exclusive scan
    __shared__ int sgbase[NBUK];              // global base per bucket
    __shared__ int wssc[4];
    int tid = threadIdx.x;
    int e0 = blockIdx.x * ACHUNK;
    int nE = N_EDGES - e0;
    if (nE > ACHUNK) nE = ACHUNK;
    for (int i = tid; i < NBUK; i += 256) scnt[i] = 0;
    __syncthreads();
    for (int i = tid; i < nE; i += 256) {
        int v = ei[N_EDGES + e0 + i];
        sv[i] = (unsigned short)v;
        atomicAdd(&scnt[v >> BSHIFT], 1);
    }
    __syncthreads();
    {
        int lane = tid & 63, w = tid >> 6;
        int val = (tid < NBUK) ? scnt[tid] : 0;
        int incl = val;
        for (int o = 1; o < 64; o <<= 1) {
            int t = __shfl_up(incl, o);
            if (lane >= o) incl += t;
        }
        if (lane == 63) wssc[w] = incl;
        __syncthreads();
        int wb = 0;
        for (int i = 0; i < w; ++i) wb += wssc[i];
        if (tid < NBUK) soff[tid] = wb + incl - val;
        if (tid == 255) soff[NBUK] = wb + incl;
    }
    __syncthreads();
    if (tid < NBUK) {
        int c = scnt[tid];
        sgbase[tid] = c ? atomicAdd(&bcur[tid], c) : 0;
        scnt[tid] = soff[tid];
    }
    __syncthreads();
    for (int i = tid; i < nE; i += 256) {
        int u = ei[e0 + i];
        unsigned v = sv[i];
        int b = (int)(v >> BSHIFT);
        int pos = atomicAdd(&scnt[b], 1);
        sdata[pos] = (unsigned)u | ((v & 255u) << 16) | ((unsigned)b << 24);
    }
    __syncthreads();
    // flush: bucket id from bits 24-31 (no binary search)
    for (int i = tid; i < nE; i += 256) {
        unsigned pk = sdata[i];
        int buk = (int)(pk >> 24);
        int rel = sgbase[buk] + (i - soff[buk]);
        if (rel < BCAP) stage[(size_t)buk * BCAP + rel] = pk;
    }
}

// ---------------- bucket-base scan: 4-aligned padded reserves ----------------

__global__ __launch_bounds__(256) void k_bukscan(const int* __restrict__ bcur, int* __restrict__ bukbase) {
    __shared__ int ws[4];
    int tid = threadIdx.x, lane = tid & 63, w = tid >> 6;
    int val = 0;
    if (tid < NBUK) {
        int base = tid << BSHIFT;
        int nv = N_NODES - base;
        if (nv > 256) nv = 256;
        val = (bcur[tid] + 4 * nv + 3) & ~3;   // upper bound on padded bucket size, 4-aligned
    }
    int incl = val;
    for (int o = 1; o < 64; o <<= 1) {
        int t = __shfl_up(incl, o);
        if (lane >= o) incl += t;
    }
    if (lane == 63) ws[w] = incl;
    __syncthreads();
    int wb = 0;
    for (int i = 0; i < w; ++i) wb += ws[i];
    if (tid < NBUK) bukbase[tid] = wb + incl - val;
}

// ---------------- Phase B: per-bucket padded CSR build (esrc u16; pads = PADU) ----------------

__global__ __launch_bounds__(256) void k_build(const unsigned* __restrict__ stage,
                                               const int* __restrict__ bcur, const int* __restrict__ bukbase,
                                               int* __restrict__ offp, int* __restrict__ ecnt,
                                               unsigned short* __restrict__ esrc) {
    __shared__ int hist[256];            // counts, then per-node cursors
    __shared__ int lexcl[257];
    __shared__ int ws[4];
    __shared__ int outbuf[5632];         // padded bucket: <= 4608 + 4*256
    int b = blockIdx.x, tid = threadIdx.x;
    int n = bcur[b];
    if (n > BCAP) n = BCAP;
    int base = b << BSHIFT;
    int nv = N_NODES - base;
    if (nv > 256) nv = 256;
    hist[tid] = 0;
    __syncthreads();
    const unsigned* sg = stage + (size_t)b * BCAP;
    for (int i = tid; i < n; i += 256) atomicAdd(&hist[(sg[i] >> 16) & 0xFF], 1);
    __syncthreads();
    int lane = tid & 63, w = tid >> 6;
    int c = (tid < nv) ? hist[tid] + 1 : 0;       // real count incl self-loop
    int r = (tid < nv) ? ((c + 3) & ~3) : 0;      // padded to multiple of 4
    int incl = r;
    for (int o = 1; o < 64; o <<= 1) {
        int t = __shfl_up(incl, o);
        if (lane >= o) incl += t;
    }
    if (lane == 63) ws[w] = incl;
    __syncthreads();
    int wb = 0;
    for (int i = 0; i < w; ++i) wb += ws[i];
    int excl = wb + incl - r;
    lexcl[tid] = excl;
    if (tid == 255) lexcl[256] = excl + r;        // padded total
    int gb = bukbase[b];
    if (tid < nv) {
        offp[base + tid] = gb + excl;             // 4-aligned (gb and excl both 4-aligned)
        ecnt[base + tid] = c;
    }
    __syncthreads();
    int total = lexcl[256];
    if (tid < nv) {
        outbuf[excl] = base + tid;                // self-loop first
        for (int j = excl + c; j < excl + r; ++j) outbuf[j] = PADU;   // pads (<=3)
        hist[tid] = 1;                            // cursor starts after self-loop
    }
    __syncthreads();
    for (int i = tid; i < n; i += 256) {
        unsigned pk = sg[i];
        int vloc = (int)((pk >> 16) & 0xFF);
        int pos = lexcl[vloc] + atomicAdd(&hist[vloc], 1);
        outbuf[pos] = (int)(pk & 0xffffu);
    }
    __syncthreads();
    for (int i = tid; i < total; i += 256) esrc[gb + i] = (unsigned short)outbuf[i];
}

// ---------------- GEMM1 via MFMA + FUSED layer-1 logits ----------------

__global__ __launch_bounds__(256) void k_gemm1m(const float* __restrict__ X, const unsigned short* __restrict__ WT,
                                                const float* __restrict__ a_src, const float* __restrict__ a_dst,
                                                unsigned char* __restrict__ H8,
                                                float* __restrict__ als, float* __restrict__ ald) {
    __shared__ unsigned short As[64][40];
    __shared__ unsigned short Bs[256][40];
    int tid = threadIdx.x;
    int row0 = blockIdx.x * 64;
    int wv = tid >> 6, lane = tid & 63;
    int wm = wv & 1, wn = wv >> 1;
    int lr = lane & 15, quad = lane >> 4;
    f32x4 acc[2][8];
#pragma unroll
    for (int mt = 0; mt < 2; ++mt)
#pragma unroll
        for (int nt = 0; nt < 8; ++nt) acc[mt][nt] = (f32x4){0.f, 0.f, 0.f, 0.f};

    int ar = tid >> 2, aseg = tid & 3;
    for (int k0 = 0; k0 < 256; k0 += 32) {
        {
            int grow = row0 + ar;
            float4 f0 = make_float4(0.f, 0.f, 0.f, 0.f), f1 = f0;
            if (grow < N_NODES) {
                const float* src = X + (size_t)grow * 256 + k0 + aseg * 8;
                f0 = *(const float4*)src;
                f1 = *(const float4*)(src + 4);
            }
            *(uint4*)&As[ar][aseg * 8] = pack_bf16_trunc(f0, f1);
        }
#pragma unroll
        for (int pass = 0; pass < 4; ++pass) {
            int q = tid + pass * 256;
            int n = q >> 2, seg = q & 3;
            uint4 v = *(const uint4*)(WT + (n << 8) + k0 + seg * 8);
            *(uint4*)&Bs[n][seg * 8] = v;
        }
        __syncthreads();
        s16x8 a[2], b[8];
#pragma unroll
        for (int mt = 0; mt < 2; ++mt) a[mt] = *(const s16x8*)&As[wm * 32 + mt * 16 + lr][quad * 8];
#pragma unroll
        for (int nt = 0; nt < 8; ++nt) b[nt] = *(const s16x8*)&Bs[wn * 128 + nt * 16 + lr][quad * 8];
#pragma unroll
        for (int mt = 0; mt < 2; ++mt)
#pragma unroll
            for (int nt = 0; nt < 8; ++nt)
                acc[mt][nt] = __builtin_amdgcn_mfma_f32_16x16x32_bf16(a[mt], b[nt], acc[mt][nt], 0, 0, 0);
        __syncthreads();
    }
#pragma unroll
    for (int mt = 0; mt < 2; ++mt) {
#pragma unroll
        for (int r = 0; r < 4; ++r) {
            int row = row0 + wm * 32 + mt * 16 + quad * 4 + r;
            if (row < N_NODES) {
#pragma unroll
                for (int nt = 0; nt < 8; ++nt) {
                    int col = wn * 128 + nt * 16 + lr;
                    H8[(size_t)row * 256 + col] = f2fp8(acc[mt][nt][r]);
                }
            }
        }
    }
    float av[8], dv[8];
#pragma unroll
    for (int nt = 0; nt < 8; ++nt) {
        int col = wn * 128 + nt * 16 + lr;
        av[nt] = a_src[col];
        dv[nt] = a_dst[col];
    }
    float ps[2][8], pd[2][8];
#pragma unroll
    for (int hl = 0; hl < 2; ++hl)
#pragma unroll
        for (int i = 0; i < 8; ++i) { ps[hl][i] = 0.f; pd[hl][i] = 0.f; }
#pragma unroll
    for (int mt = 0; mt < 2; ++mt)
#pragma unroll
        for (int nt = 0; nt < 8; ++nt) {
            int hl = nt >> 2;
#pragma unroll
            for (int r = 0; r < 4; ++r) {
                float v = acc[mt][nt][r];
                ps[hl][mt * 4 + r] = fmaf(v, av[nt], ps[hl][mt * 4 + r]);
                pd[hl][mt * 4 + r] = fmaf(v, dv[nt], pd[hl][mt * 4 + r]);
            }
        }
#pragma unroll
    for (int hl = 0; hl < 2; ++hl)
#pragma unroll
        for (int i = 0; i < 8; ++i) {
            float s = ps[hl][i], d = pd[hl][i];
#pragma unroll
            for (int m = 8; m >= 1; m >>= 1) { s += __shfl_xor(s, m); d += __shfl_xor(d, m); }
            if (lr == 0) {
                int row = row0 + wm * 32 + (i >> 2) * 16 + quad * 4 + (i & 3);
                if (row < N_NODES) {
                    als[row * 4 + wn * 2 + hl] = s;
                    ald[row * 4 + wn * 2 + hl] = d;
                }
            }
        }
}

// ---------------- Layer-1 aggregation: wave-per-node, padded segments, ZERO singles ----------------

__global__ __launch_bounds__(256) void k_agg1(const unsigned* __restrict__ H8u,
                                              const float* __restrict__ als, const float* __restrict__ ald_,
                                              const int* __restrict__ offp, const int* __restrict__ ecnt,
                                              const unsigned short* __restrict__ esrc,
                                              const float* __restrict__ b1, unsigned* __restrict__ H2p) {
    int wid = (blockIdx.x * 256 + threadIdx.x) >> 6;   // grid = N/4 -> wid < N
    int lane = threadIdx.x & 63;
    int head = lane >> 4;
    float ald = ald_[wid * 4 + head];
    int pstart = offp[wid];
    int rend = pstart + ((ecnt[wid] + 3) & ~3);
    float l = 0.f, ax = 0.f, ay = 0.f, az = 0.f, aw = 0.f;

    auto quad = [&](unsigned ua, unsigned ub) {
        int u0 = (int)(ua & 0xffffu), u1 = (int)(ua >> 16);
        int u2 = (int)(ub & 0xffffu), u3 = (int)(ub >> 16);
        // gather clamps pad (u=50000) to a valid row; its weight is exactly 0
        unsigned v0 = H8u[(unsigned)min(u0, N_NODES - 1) * 64 + lane];
        unsigned v1 = H8u[(unsigned)min(u1, N_NODES - 1) * 64 + lane];
        unsigned v2 = H8u[(unsigned)min(u2, N_NODES - 1) * 64 + lane];
        unsigned v3 = H8u[(unsigned)min(u3, N_NODES - 1) * 64 + lane];
        float e0 = als[u0 * 4 + head] + ald;   // pad row = -1e30 -> exp 0
        float e1 = als[u1 * 4 + head] + ald;
        float e2 = als[u2 * 4 + head] + ald;
        float e3 = als[u3 * 4 + head] + ald;
        e0 = fmaxf(e0, NEG_SLOPE * e0);
        e1 = fmaxf(e1, NEG_SLOPE * e1);
        e2 = fmaxf(e2, NEG_SLOPE * e2);
        e3 = fmaxf(e3, NEG_SLOPE * e3);
        float pw0 = __expf(e0), pw1 = __expf(e1), pw2 = __expf(e2), pw3 = __expf(e3);
        l += (pw0 + pw1) + (pw2 + pw3);
        f32x2 a0 = __builtin_amdgcn_cvt_pk_f32_fp8(v0, false), b0 = __builtin_amdgcn_cvt_pk_f32_fp8(v0, true);
        f32x2 a1 = __builtin_amdgcn_cvt_pk_f32_fp8(v1, false), b1v = __builtin_amdgcn_cvt_pk_f32_fp8(v1, true);
        f32x2 a2 = __builtin_amdgcn_cvt_pk_f32_fp8(v2, false), b2v = __builtin_amdgcn_cvt_pk_f32_fp8(v2, true);
        f32x2 a3 = __builtin_amdgcn_cvt_pk_f32_fp8(v3, false), b3v = __builtin_amdgcn_cvt_pk_f32_fp8(v3, true);
        ax = fmaf(pw3, a3.x, fmaf(pw2, a2.x, fmaf(pw1, a1.x, fmaf(pw0, a0.x, ax))));
        ay = fmaf(pw3, a3.y, fmaf(pw2, a2.y, fmaf(pw1, a1.y, fmaf(pw0, a0.y, ay))));
        az = fmaf(pw3, b3v.x, fmaf(pw2, b2v.x, fmaf(pw1, b1v.x, fmaf(pw0, b0.x, az))));
        aw = fmaf(pw3, b3v.y, fmaf(pw2, b2v.y, fmaf(pw1, b1v.y, fmaf(pw0, b0.y, aw))));
    };

    int p = pstart;
    for (; p + 7 < rend; p += 8) {
        uint2 ua = *(const uint2*)(esrc + p);
        uint2 ub = *(const uint2*)(esrc + p + 4);
        quad(ua.x, ua.y);
        quad(ub.x, ub.y);
    }
    if (p < rend) {
        uint2 ua = *(const uint2*)(esrc + p);
        quad(ua.x, ua.y);
    }

    float inv = 1.f / l;
    int c = lane * 4;
    float4 bb = *(const float4*)(b1 + c);
    float o0 = ax * inv + bb.x, o1 = ay * inv + bb.y, o2 = az * inv + bb.z, o3 = aw * inv + bb.w;
    o0 = o0 > 0.f ? o0 : expm1f(o0);
    o1 = o1 > 0.f ? o1 : expm1f(o1);
    o2 = o2 > 0.f ? o2 : expm1f(o2);
    o3 = o3 > 0.f ? o3 : expm1f(o3);
    unsigned pk = __builtin_amdgcn_cvt_pk_fp8_f32(o0, o1, 0, false);
    pk = __builtin_amdgcn_cvt_pk_fp8_f32(o2, o3, pk, true);
    H2p[(unsigned)wid * 64 + lane] = pk;
}

// ---------------- GEMM2 via MFMA: g = h2(fp8->bf16) @ W2(bf16) + layer-2 logits ----------------

__global__ __launch_bounds__(256) void k_gemm2m(const unsigned* __restrict__ H2p,
                                                const unsigned short* __restrict__ W2T,
                                                const float* __restrict__ as2, const float* __restrict__ ad2,
                                                unsigned short* __restrict__ Gb, float* __restrict__ als2,
                                                float* __restrict__ ald2) {
    int tid = threadIdx.x;
    int wv = tid >> 6, lane = tid & 63, lr = lane & 15, quad = lane >> 4;
    int row0 = blockIdx.x * 64 + wv * 16;
    int rowA = row0 + lr;
    unsigned rA = (rowA < N_NODES) ? (unsigned)rowA : (unsigned)(N_NODES - 1);
    f32x4 acc[2];
    acc[0] = (f32x4){0.f, 0.f, 0.f, 0.f};
    acc[1] = (f32x4){0.f, 0.f, 0.f, 0.f};
#pragma unroll
    for (int k0 = 0; k0 < 256; k0 += 32) {
        uint2 d = *(const uint2*)(H2p + rA * 64 + (k0 >> 2) + quad * 2);
        f32x2 f0 = __builtin_amdgcn_cvt_pk_f32_fp8(d.x, false);
        f32x2 f1 = __builtin_amdgcn_cvt_pk_f32_fp8(d.x, true);
        f32x2 f2 = __builtin_amdgcn_cvt_pk_f32_fp8(d.y, false);
        f32x2 f3 = __builtin_amdgcn_cvt_pk_f32_fp8(d.y, true);
        union { uint4 u; s16x8 s; } cv;
        cv.u = pack_bf16_trunc(make_float4(f0.x, f0.y, f1.x, f1.y), make_float4(f2.x, f2.y, f3.x, f3.y));
        s16x8 afrag = cv.s;
        s16x8 b0 = *(const s16x8*)(W2T + lr * 256 + k0 + quad * 8);
        s16x8 b1f = *(const s16x8*)(W2T + (16 + lr) * 256 + k0 + quad * 8);
        acc[0] = __builtin_amdgcn_mfma_f32_16x16x32_bf16(afrag, b0, acc[0], 0, 0, 0);
        acc[1] = __builtin_amdgcn_mfma_f32_16x16x32_bf16(afrag, b1f, acc[1], 0, 0, 0);
    }
    float a2s = as2[lr], a2s2 = as2[16 + lr];
    float a2d = ad2[lr], a2d2 = ad2[16 + lr];
#pragma unroll
    for (int r = 0; r < 4; ++r) {
        int row = row0 + quad * 4 + r;
        float g0 = acc[0][r], g1 = acc[1][r];
        float s = g0 * a2s + g1 * a2s2;
        float dd = g0 * a2d + g1 * a2d2;
#pragma unroll
        for (int m = 8; m >= 1; m >>= 1) { s += __shfl_xor(s, m); dd += __shfl_xor(dd, m); }
        if (row < N_NODES) {
            Gb[(size_t)row * 32 + lr] = f2bf(g0);
            Gb[(size_t)row * 32 + 16 + lr] = f2bf(g1);
            if (lr == 0) { als2[row] = s; ald2[row] = dd; }
        }
    }
}

// ---------------- Layer-2 aggregation + bias + log_softmax (aligned start, inline exp) ----------------

__global__ __launch_bounds__(256) void k_agg2(const unsigned short* __restrict__ Gb,
                                              const float* __restrict__ als2,
                                              const float* __restrict__ ald2_, const int* __restrict__ offp,
                                              const int* __restrict__ ecnt,
                                              const unsigned short* __restrict__ esrc, const float* __restrict__ b2,
                                              float* __restrict__ out) {
    int gid = blockIdx.x * 256 + threadIdx.x;
    int node = gid >> 5;
    int col = gid & 31;
    if (node >= N_NODES) return;
    float ald = ald2_[node];
    int pstart = offp[node];                  // 4-aligned
    int pend = pstart + ecnt[node];           // real end (pads excluded)
    float l = 0.f, acc = 0.f;

    auto edge1 = [&](int u0) {
        float g0 = bf2f(Gb[(size_t)(unsigned)u0 * 32 + col]);
        float e0 = als2[u0] + ald;
        e0 = fmaxf(e0, NEG_SLOPE * e0);
        float pw0 = __expf(e0);
        l += pw0;
        acc = fmaf(pw0, g0, acc);
    };
    auto quad = [&](unsigned ua, unsigned ub) {
        int u0 = (int)(ua & 0xffffu), u1 = (int)(ua >> 16);
        int u2 = (int)(ub & 0xffffu), u3 = (int)(ub >> 16);
        float g0 = bf2f(Gb[(size_t)(unsigned)u0 * 32 + col]);
        float g1 = bf2f(Gb[(size_t)(unsigned)u1 * 32 + col]);
        float g2 = bf2f(Gb[(size_t)(unsigned)u2 * 32 + col]);
        float g3 = bf2f(Gb[(size_t)(unsigned)u3 * 32 + col]);
        float e0 = als2[u0] + ald, e1 = als2[u1] + ald, e2 = als2[u2] + ald, e3 = als2[u3] + ald;
        e0 = fmaxf(e0, NEG_SLOPE * e0); e1 = fmaxf(e1, NEG_SLOPE * e1);
        e2 = fmaxf(e2, NEG_SLOPE * e2); e3 = fmaxf(e3, NEG_SLOPE * e3);
        float pw0 = __expf(e0), pw1 = __expf(e1), pw2 = __expf(e2), pw3 = __expf(e3);
        l += (pw0 + pw1) + (pw2 + pw3);
        acc = fmaf(pw3, g3, fmaf(pw2, g2, fmaf(pw1, g1, fmaf(pw0, g0, acc))));
    };

    int p = pstart;
    for (; p + 7 < pend; p += 8) {
        uint2 ua = *(const uint2*)(esrc + p);
        uint2 ub = *(const uint2*)(esrc + p + 4);
        quad(ua.x, ua.y);
        quad(ub.x, ub.y);
    }
    for (; p + 3 < pend; p += 4) {
        uint2 ua = *(const uint2*)(esrc + p);
        quad(ua.x, ua.y);
    }
    for (; p < pend; ++p) edge1(esrc[p]);

    float o = acc / l + b2[col];
    float mm = o;
#pragma unroll
    for (int msk = 16; msk >= 1; msk >>= 1) mm = fmaxf(mm, __shfl_xor(mm, msk));
    float ex = __expf(o - mm);
    float s = ex;
#pragma unroll
    for (int msk = 16; msk >= 1; msk >>= 1) s += __shfl_xor(s, msk);
    out[(size_t)node * 32 + col] = o - mm - logf(s);
}

// ---------------- launch ----------------

extern "C" void kernel_launch(void* const* d_in, const int* in_sizes, int n_in,
                              void* d_out, int out_size, void* d_ws, size_t ws_size,
                              hipStream_t stream) {
    const float* x   = (const float*)d_in[0];
    const int*   ei  = (const int*)d_in[1];
    const float* W1  = (const float*)d_in[2];
    const float* as1 = (const float*)d_in[3];
    const float* ad1 = (const float*)d_in[4];
    const float* b1  = (const float*)d_in[5];
    const float* W2  = (const float*)d_in[6];
    const float* as2 = (const float*)d_in[7];
    const float* ad2 = (const float*)d_in[8];
    const float* b2  = (const float*)d_in[9];
    float* out = (float*)d_out;

    char* p = (char*)d_ws;
    auto alloc = [&](size_t bytes) {
        char* r = p;
        p += (bytes + 255) & ~(size_t)255;
        return r;
    };
    // workspace ~30 MB (stage aliases h2p; g aliases h8 — disjoint lifetimes)
    unsigned char*  h8  = (unsigned char*)alloc((size_t)N_NODES * 256);        // 12.8 MB fp8 h1
    unsigned char*  h2pr= (unsigned char*)alloc((size_t)N_NODES * 64 * 4);     // 12.8 MB fp8 h2 packed
    unsigned short* wt  = (unsigned short*)alloc((size_t)256 * 256 * 2);       // 128 KB bf16 W1^T
    unsigned short* w2t = (unsigned short*)alloc((size_t)32 * 256 * 2);        // 16 KB bf16 W2^T
    float* als1 = (float*)alloc(((size_t)N_NODES * 4 + 4) * 4);                // +1 pad-sentinel row
    float* ald1 = (float*)alloc((size_t)N_NODES * 4 * 4);
    float* als2 = (float*)alloc((size_t)N_NODES * 4);
    float* ald2 = (float*)alloc((size_t)N_NODES * 4);
    int* bcur    = (int*)alloc(256 * 4);
    int* bukbase = (int*)alloc(256 * 4);
    int* offp = (int*)alloc((size_t)N_NODES * 4);
    int* ecnt = (int*)alloc((size_t)N_NODES * 4);
    unsigned short* esrc = (unsigned short*)alloc((size_t)ET_PAD_ALLOC * 2);   // 2.0 MB u16, padded CSR

    // aliases (disjoint lifetimes):
    unsigned* stage = (unsigned*)h2pr;                 // 3.6 MB (k_bin -> k_build; dead before agg1 writes h2p)
    unsigned* h2p = (unsigned*)h2pr;
    unsigned short* g = (unsigned short*)h8;           // 3.2 MB bf16 (written by gemm2m after h8 dead)

    k_cvtw<<<289, 256, 0, stream>>>(W1, W2, wt, w2t, bcur, als1);              // zeroes bcur, sets pad row
    k_bin<<<(N_EDGES + ACHUNK - 1) / ACHUNK, 256, 0, stream>>>(ei, bcur, stage);
    k_bukscan<<<1, 256, 0, stream>>>(bcur, bukbase);
    k_build<<<NBUK, 256, 0, stream>>>(stage, bcur, bukbase, offp, ecnt, esrc);

    k_gemm1m<<<(N_NODES + 63) / 64, 256, 0, stream>>>(x, wt, as1, ad1, h8, als1, ald1);
    k_agg1<<<N_NODES / 4, 256, 0, stream>>>((const unsigned*)h8, als1, ald1, offp, ecnt, esrc, b1, h2p);
    k_gemm2m<<<(N_NODES + 63) / 64, 256, 0, stream>>>(h2p, w2t, as2, ad2, g, als2, ald2);
    k_agg2<<<(N_NODES * 32 + 255) / 256, 256, 0, stream>>>(g, als2, ald2, offp, ecnt, esrc, b2, out);
}

// Round 8
// 222.927 us; speedup vs baseline: 1.2727x; 1.0187x over previous
//
#include <hip/hip_runtime.h>
#include <math.h>

#define N_NODES 50000
#define N_EDGES 800000
#define NEG_SLOPE 0.2f
#define PADU N_NODES               // pad sentinel source index (als1 row=-1e30, h8 row=0)
#define LOG2E 1.44269504088896f

// binned scatter params: 256-node buckets
#define BSHIFT 8
#define NBUK ((N_NODES + 255) >> BSHIFT)    // 196 buckets
#define BCAP 4608                           // per-bucket capacity (mean 4096, +8 sigma)
#define ACHUNK 4096                         // edges per k_bin block
#define ET_PAD_ALLOC 1000960                // >= sum of per-bucket padded reserves

typedef __attribute__((ext_vector_type(8))) short s16x8;
typedef __attribute__((ext_vector_type(4))) float f32x4;
typedef __attribute__((ext_vector_type(2))) float f32x2;

__device__ __forceinline__ unsigned short f2bf(float f) {
    union { float f; unsigned u; } v; v.f = f;
    unsigned r = v.u + 0x7FFF + ((v.u >> 16) & 1);  // RNE
    return (unsigned short)(r >> 16);
}
__device__ __forceinline__ float asf(unsigned u) {
    union { unsigned u; float f; } v; v.u = u;
    return v.f;
}
// truncation-pack 8 fp32 -> 8 bf16
__device__ __forceinline__ uint4 pack_bf16_trunc(float4 f0, float4 f1) {
    const unsigned* a = (const unsigned*)&f0;
    const unsigned* b = (const unsigned*)&f1;
    uint4 r;
    r.x = (a[0] >> 16) | (a[1] & 0xffff0000u);
    r.y = (a[2] >> 16) | (a[3] & 0xffff0000u);
    r.z = (b[0] >> 16) | (b[1] & 0xffff0000u);
    r.w = (b[2] >> 16) | (b[3] & 0xffff0000u);
    return r;
}
// fp8 e4m3 (OCP) — HW convert
__device__ __forceinline__ unsigned char f2fp8(float f) {
    return (unsigned char)(__builtin_amdgcn_cvt_pk_fp8_f32(f, f, 0, false) & 0xff);
}

// ---------------- weight converts + bcur zeroing + pad-sentinel rows ----------------

__global__ __launch_bounds__(256) void k_cvtw(const float* __restrict__ W1, const float* __restrict__ W2,
                                              unsigned short* __restrict__ WT, unsigned short* __restrict__ W2T,
                                              int* __restrict__ bcur, float* __restrict__ als1,
                                              unsigned char* __restrict__ H8) {
    int b = blockIdx.x, k = threadIdx.x;
    if (b < 256) {
        WT[b * 256 + k] = f2bf(W1[k * 256 + b]);
    } else if (b < 288) {
        int c = b - 256;
        W2T[c * 256 + k] = f2bf(W2[k * 32 + c]);
    } else {
        if (k < NBUK) bcur[k] = 0;
        if (k >= 196 && k < 200) als1[N_NODES * 4 + (k - 196)] = -1e30f;        // pad row: exp2 -> 0
        if (k >= 200 && k < 264) ((unsigned*)(H8 + (size_t)N_NODES * 256))[k - 200] = 0;  // h8 pad row = 0
    }
}

// ---------------- Phase A: LDS-binned edge staging (bucket id packed in bits 24-31) ----------------

__global__ __launch_bounds__(256) void k_bin(const int* __restrict__ ei, int* __restrict__ bcur,
                                             unsigned* __restrict__ stage) {
    __shared__ unsigned sdata[ACHUNK];        // u | vloc<<16 | buk<<24, bucket-major
    __shared__ unsigned short sv[ACHUNK];     // v cached between passes (v < 65536)
    __shared__ int scnt[NBUK];                // counts, then pass-2 cursors
    __shared__ int soff[NBUK + 1];            // exclusive scan
    __shared__ int sgbase[NBUK];              // global base per bucket
    __shared__ int wssc[4];
    int tid = threadIdx.x;
    int e0 = blockIdx.x * ACHUNK;
    int nE = N_EDGES - e0;
    if (nE > ACHUNK) nE = ACHUNK;
    for (int i = tid; i < NBUK; i += 256) scnt[i] = 0;
    __syncthreads();
    for (int i = tid; i < nE; i += 256) {
        int v = ei[N_EDGES + e0 + i];
        sv[i] = (unsigned short)v;
        atomicAdd(&scnt[v >> BSHIFT], 1);
    }
    __syncthreads();
    {
        int lane = tid & 63, w = tid >> 6;
        int val = (tid < NBUK) ? scnt[tid] : 0;
        int incl = val;
        for (int o = 1; o < 64; o <<= 1) {
            int t = __shfl_up(incl, o);
            if (lane >= o) incl += t;
        }
        if (lane == 63) wssc[w] = incl;
        __syncthreads();
        int wb = 0;
        for (int i = 0; i < w; ++i) wb += wssc[i];
        if (tid < NBUK) soff[tid] = wb + incl - val;
        if (tid == 255) soff[NBUK] = wb + incl;
    }
    __syncthreads();
    if (tid < NBUK) {
        int c = scnt[tid];
        sgbase[tid] = c ? atomicAdd(&bcur[tid], c) : 0;
        scnt[tid] = soff[tid];
    }
    __syncthreads();
    for (int i = tid; i < nE; i += 256) {
        int u = ei[e0 + i];
        unsigned v = sv[i];
        int b = (int)(v >> BSHIFT);
        int pos = atomicAdd(&scnt[b], 1);
        sdata[pos] = (unsigned)u | ((v & 255u) << 16) | ((unsigned)b << 24);
    }
    __syncthreads();
    // flush: bucket id from bits 24-31 (no binary search)
    for (int i = tid; i < nE; i += 256) {
        unsigned pk = sdata[i];
        int buk = (int)(pk >> 24);
        int rel = sgbase[buk] + (i - soff[buk]);
        if (rel < BCAP) stage[(size_t)buk * BCAP + rel] = pk;
    }
}

// ---------------- bucket-base scan: 4-aligned padded reserves ----------------

__global__ __launch_bounds__(256) void k_bukscan(const int* __restrict__ bcur, int* __restrict__ bukbase) {
    __shared__ int ws[4];
    int tid = threadIdx.x, lane = tid & 63, w = tid >> 6;
    int val = 0;
    if (tid < NBUK) {
        int base = tid << BSHIFT;
        int nv = N_NODES - base;
        if (nv > 256) nv = 256;
        val = (bcur[tid] + 4 * nv + 3) & ~3;   // upper bound on padded bucket size, 4-aligned
    }
    int incl = val;
    for (int o = 1; o < 64; o <<= 1) {
        int t = __shfl_up(incl, o);
        if (lane >= o) incl += t;
    }
    if (lane == 63) ws[w] = incl;
    __syncthreads();
    int wb = 0;
    for (int i = 0; i < w; ++i) wb += ws[i];
    if (tid < NBUK) bukbase[tid] = wb + incl - val;
}

// ---------------- Phase B: per-bucket padded CSR build (esrc u16; pads = PADU) ----------------

__global__ __launch_bounds__(256) void k_build(const unsigned* __restrict__ stage,
                                               const int* __restrict__ bcur, const int* __restrict__ bukbase,
                                               int* __restrict__ offp, int* __restrict__ ecnt,
                                               unsigned short* __restrict__ esrc) {
    __shared__ int hist[256];            // counts, then per-node cursors
    __shared__ int lexcl[257];
    __shared__ int ws[4];
    __shared__ int outbuf[5632];         // padded bucket: <= 4608 + 4*256
    int b = blockIdx.x, tid = threadIdx.x;
    int n = bcur[b];
    if (n > BCAP) n = BCAP;
    int base = b << BSHIFT;
    int nv = N_NODES - base;
    if (nv > 256) nv = 256;
    hist[tid] = 0;
    __syncthreads();
    const unsigned* sg = stage + (size_t)b * BCAP;
    for (int i = tid; i < n; i += 256) atomicAdd(&hist[(sg[i] >> 16) & 0xFF], 1);
    __syncthreads();
    int lane = tid & 63, w = tid >> 6;
    int c = (tid < nv) ? hist[tid] + 1 : 0;       // real count incl self-loop
    int r = (tid < nv) ? ((c + 3) & ~3) : 0;      // padded to multiple of 4
    int incl = r;
    for (int o = 1; o < 64; o <<= 1) {
        int t = __shfl_up(incl, o);
        if (lane >= o) incl += t;
    }
    if (lane == 63) ws[w] = incl;
    __syncthreads();
    int wb = 0;
    for (int i = 0; i < w; ++i) wb += ws[i];
    int excl = wb + incl - r;
    lexcl[tid] = excl;
    if (tid == 255) lexcl[256] = excl + r;        // padded total
    int gb = bukbase[b];
    if (tid < nv) {
        offp[base + tid] = gb + excl;             // 4-aligned (gb and excl both 4-aligned)
        ecnt[base + tid] = c;
    }
    __syncthreads();
    int total = lexcl[256];
    if (tid < nv) {
        outbuf[excl] = base + tid;                // self-loop first
        for (int j = excl + c; j < excl + r; ++j) outbuf[j] = PADU;   // pads (<=3)
        hist[tid] = 1;                            // cursor starts after self-loop
    }
    __syncthreads();
    for (int i = tid; i < n; i += 256) {
        unsigned pk = sg[i];
        int vloc = (int)((pk >> 16) & 0xFF);
        int pos = lexcl[vloc] + atomicAdd(&hist[vloc], 1);
        outbuf[pos] = (int)(pk & 0xffffu);
    }
    __syncthreads();
    for (int i = tid; i < total; i += 256) esrc[gb + i] = (unsigned short)outbuf[i];
}

// ---------------- GEMM1 via MFMA + FUSED layer-1 logits (logits pre-scaled by LOG2E) ----------------

__global__ __launch_bounds__(256) void k_gemm1m(const float* __restrict__ X, const unsigned short* __restrict__ WT,
                                                const float* __restrict__ a_src, const float* __restrict__ a_dst,
                                                unsigned char* __restrict__ H8,
                                                float* __restrict__ als, float* __restrict__ ald) {
    __shared__ unsigned short As[64][40];
    __shared__ unsigned short Bs[256][40];
    int tid = threadIdx.x;
    int row0 = blockIdx.x * 64;
    int wv = tid >> 6, lane = tid & 63;
    int wm = wv & 1, wn = wv >> 1;
    int lr = lane & 15, quad = lane >> 4;
    f32x4 acc[2][8];
#pragma unroll
    for (int mt = 0; mt < 2; ++mt)
#pragma unroll
        for (int nt = 0; nt < 8; ++nt) acc[mt][nt] = (f32x4){0.f, 0.f, 0.f, 0.f};

    int ar = tid >> 2, aseg = tid & 3;
    for (int k0 = 0; k0 < 256; k0 += 32) {
        {
            int grow = row0 + ar;
            float4 f0 = make_float4(0.f, 0.f, 0.f, 0.f), f1 = f0;
            if (grow < N_NODES) {
                const float* src = X + (size_t)grow * 256 + k0 + aseg * 8;
                f0 = *(const float4*)src;
                f1 = *(const float4*)(src + 4);
            }
            *(uint4*)&As[ar][aseg * 8] = pack_bf16_trunc(f0, f1);
        }
#pragma unroll
        for (int pass = 0; pass < 4; ++pass) {
            int q = tid + pass * 256;
            int n = q >> 2, seg = q & 3;
            uint4 v = *(const uint4*)(WT + (n << 8) + k0 + seg * 8);
            *(uint4*)&Bs[n][seg * 8] = v;
        }
        __syncthreads();
        s16x8 a[2], b[8];
#pragma unroll
        for (int mt = 0; mt < 2; ++mt) a[mt] = *(const s16x8*)&As[wm * 32 + mt * 16 + lr][quad * 8];
#pragma unroll
        for (int nt = 0; nt < 8; ++nt) b[nt] = *(const s16x8*)&Bs[wn * 128 + nt * 16 + lr][quad * 8];
#pragma unroll
        for (int mt = 0; mt < 2; ++mt)
#pragma unroll
            for (int nt = 0; nt < 8; ++nt)
                acc[mt][nt] = __builtin_amdgcn_mfma_f32_16x16x32_bf16(a[mt], b[nt], acc[mt][nt], 0, 0, 0);
        __syncthreads();
    }
#pragma unroll
    for (int mt = 0; mt < 2; ++mt) {
#pragma unroll
        for (int r = 0; r < 4; ++r) {
            int row = row0 + wm * 32 + mt * 16 + quad * 4 + r;
            if (row < N_NODES) {
#pragma unroll
                for (int nt = 0; nt < 8; ++nt) {
                    int col = wn * 128 + nt * 16 + lr;
                    H8[(size_t)row * 256 + col] = f2fp8(acc[mt][nt][r]);
                }
            }
        }
    }
    float av[8], dv[8];
#pragma unroll
    for (int nt = 0; nt < 8; ++nt) {
        int col = wn * 128 + nt * 16 + lr;
        av[nt] = a_src[col] * LOG2E;   // pre-scale: downstream uses exp2
        dv[nt] = a_dst[col] * LOG2E;
    }
    float ps[2][8], pd[2][8];
#pragma unroll
    for (int hl = 0; hl < 2; ++hl)
#pragma unroll
        for (int i = 0; i < 8; ++i) { ps[hl][i] = 0.f; pd[hl][i] = 0.f; }
#pragma unroll
    for (int mt = 0; mt < 2; ++mt)
#pragma unroll
        for (int nt = 0; nt < 8; ++nt) {
            int hl = nt >> 2;
#pragma unroll
            for (int r = 0; r < 4; ++r) {
                float v = acc[mt][nt][r];
                ps[hl][mt * 4 + r] = fmaf(v, av[nt], ps[hl][mt * 4 + r]);
                pd[hl][mt * 4 + r] = fmaf(v, dv[nt], pd[hl][mt * 4 + r]);
            }
        }
#pragma unroll
    for (int hl = 0; hl < 2; ++hl)
#pragma unroll
        for (int i = 0; i < 8; ++i) {
            float s = ps[hl][i], d = pd[hl][i];
#pragma unroll
            for (int m = 8; m >= 1; m >>= 1) { s += __shfl_xor(s, m); d += __shfl_xor(d, m); }
            if (lr == 0) {
                int row = row0 + wm * 32 + (i >> 2) * 16 + quad * 4 + (i & 3);
                if (row < N_NODES) {
                    als[row * 4 + wn * 2 + hl] = s;
                    ald[row * 4 + wn * 2 + hl] = d;
                }
            }
        }
}

// ---------------- Layer-1 aggregation: padded segments, pk-fma, direct v_exp ----------------

__global__ __launch_bounds__(256) void k_agg1(const unsigned* __restrict__ H8u,
                                              const float* __restrict__ als, const float* __restrict__ ald_,
                                              const int* __restrict__ offp, const int* __restrict__ ecnt,
                                              const unsigned short* __restrict__ esrc,
                                              const float* __restrict__ b1, unsigned* __restrict__ H2p) {
    int wid = (blockIdx.x * 256 + threadIdx.x) >> 6;   // grid = N/4 -> wid < N
    int lane = threadIdx.x & 63;
    int head = lane >> 4;
    float ald = ald_[wid * 4 + head];
    int pstart = offp[wid];
    int rend = pstart + ((ecnt[wid] + 3) & ~3);
    float l = 0.f;
    f32x2 axy = (f32x2){0.f, 0.f}, azw = (f32x2){0.f, 0.f};

    auto quad = [&](unsigned ua, unsigned ub) {
        int u0 = (int)(ua & 0xffffu), u1 = (int)(ua >> 16);
        int u2 = (int)(ub & 0xffffu), u3 = (int)(ub >> 16);
        // pads (u=50000) read the zeroed h8 row and the -1e30 als row -> contribute 0
        unsigned v0 = H8u[(unsigned)u0 * 64 + lane];
        unsigned v1 = H8u[(unsigned)u1 * 64 + lane];
        unsigned v2 = H8u[(unsigned)u2 * 64 + lane];
        unsigned v3 = H8u[(unsigned)u3 * 64 + lane];
        f32x2 e01 = (f32x2){als[u0 * 4 + head], als[u1 * 4 + head]} + (f32x2){ald, ald};
        f32x2 e23 = (f32x2){als[u2 * 4 + head], als[u3 * 4 + head]} + (f32x2){ald, ald};
        f32x2 t01 = e01 * NEG_SLOPE, t23 = e23 * NEG_SLOPE;   // v_pk_mul_f32
        float e0 = fmaxf(e01.x, t01.x), e1 = fmaxf(e01.y, t01.y);
        float e2 = fmaxf(e23.x, t23.x), e3 = fmaxf(e23.y, t23.y);
        float pw0 = __builtin_amdgcn_exp2f(e0);   // logits pre-scaled by LOG2E
        float pw1 = __builtin_amdgcn_exp2f(e1);
        float pw2 = __builtin_amdgcn_exp2f(e2);
        float pw3 = __builtin_amdgcn_exp2f(e3);
        l += (pw0 + pw1) + (pw2 + pw3);
        f32x2 a0 = __builtin_amdgcn_cvt_pk_f32_fp8(v0, false), b0 = __builtin_amdgcn_cvt_pk_f32_fp8(v0, true);
        f32x2 a1 = __builtin_amdgcn_cvt_pk_f32_fp8(v1, false), b1v = __builtin_amdgcn_cvt_pk_f32_fp8(v1, true);
        f32x2 a2 = __builtin_amdgcn_cvt_pk_f32_fp8(v2, false), b2v = __builtin_amdgcn_cvt_pk_f32_fp8(v2, true);
        f32x2 a3 = __builtin_amdgcn_cvt_pk_f32_fp8(v3, false), b3v = __builtin_amdgcn_cvt_pk_f32_fp8(v3, true);
        axy += (f32x2){pw0, pw0} * a0;   // v_pk_fma_f32
        azw += (f32x2){pw0, pw0} * b0;
        axy += (f32x2){pw1, pw1} * a1;
        azw += (f32x2){pw1, pw1} * b1v;
        axy += (f32x2){pw2, pw2} * a2;
        azw += (f32x2){pw2, pw2} * b2v;
        axy += (f32x2){pw3, pw3} * a3;
        azw += (f32x2){pw3, pw3} * b3v;
    };

    int p = pstart;
    for (; p + 7 < rend; p += 8) {
        uint2 ua = *(const uint2*)(esrc + p);
        uint2 ub = *(const uint2*)(esrc + p + 4);
        quad(ua.x, ua.y);
        quad(ub.x, ub.y);
    }
    if (p < rend) {
        uint2 ua = *(const uint2*)(esrc + p);
        quad(ua.x, ua.y);
    }

    float inv = 1.f / l;
    int c = lane * 4;
    float4 bb = *(const float4*)(b1 + c);
    float o0 = axy.x * inv + bb.x, o1 = axy.y * inv + bb.y, o2 = azw.x * inv + bb.z, o3 = azw.y * inv + bb.w;
    o0 = o0 > 0.f ? o0 : expm1f(o0);
    o1 = o1 > 0.f ? o1 : expm1f(o1);
    o2 = o2 > 0.f ? o2 : expm1f(o2);
    o3 = o3 > 0.f ? o3 : expm1f(o3);
    unsigned pk = __builtin_amdgcn_cvt_pk_fp8_f32(o0, o1, 0, false);
    pk = __builtin_amdgcn_cvt_pk_fp8_f32(o2, o3, pk, true);
    H2p[(unsigned)wid * 64 + lane] = pk;
}

// ---------------- GEMM2 via MFMA: g = h2(fp8->bf16) @ W2(bf16) + layer-2 logits (pre-scaled) ----------------

__global__ __launch_bounds__(256) void k_gemm2m(const unsigned* __restrict__ H2p,
                                                const unsigned short* __restrict__ W2T,
                                                const float* __restrict__ as2, const float* __restrict__ ad2,
                                                unsigned short* __restrict__ Gb, float* __restrict__ als2,
                                                float* __restrict__ ald2) {
    int tid = threadIdx.x;
    int wv = tid >> 6, lane = tid & 63, lr = lane & 15, quad = lane >> 4;
    int row0 = blockIdx.x * 64 + wv * 16;
    int rowA = row0 + lr;
    unsigned rA = (rowA < N_NODES) ? (unsigned)rowA : (unsigned)(N_NODES - 1);
    f32x4 acc[2];
    acc[0] = (f32x4){0.f, 0.f, 0.f, 0.f};
    acc[1] = (f32x4){0.f, 0.f, 0.f, 0.f};
#pragma unroll
    for (int k0 = 0; k0 < 256; k0 += 32) {
        uint2 d = *(const uint2*)(H2p + rA * 64 + (k0 >> 2) + quad * 2);
        f32x2 f0 = __builtin_amdgcn_cvt_pk_f32_fp8(d.x, false);
        f32x2 f1 = __builtin_amdgcn_cvt_pk_f32_fp8(d.x, true);
        f32x2 f2 = __builtin_amdgcn_cvt_pk_f32_fp8(d.y, false);
        f32x2 f3 = __builtin_amdgcn_cvt_pk_f32_fp8(d.y, true);
        union { uint4 u; s16x8 s; } cv;
        cv.u = pack_bf16_trunc(make_float4(f0.x, f0.y, f1.x, f1.y), make_float4(f2.x, f2.y, f3.x, f3.y));
        s16x8 afrag = cv.s;
        s16x8 b0 = *(const s16x8*)(W2T + lr * 256 + k0 + quad * 8);
        s16x8 b1f = *(const s16x8*)(W2T + (16 + lr) * 256 + k0 + quad * 8);
        acc[0] = __builtin_amdgcn_mfma_f32_16x16x32_bf16(afrag, b0, acc[0], 0, 0, 0);
        acc[1] = __builtin_amdgcn_mfma_f32_16x16x32_bf16(afrag, b1f, acc[1], 0, 0, 0);
    }
    float a2s = as2[lr] * LOG2E, a2s2 = as2[16 + lr] * LOG2E;
    float a2d = ad2[lr] * LOG2E, a2d2 = ad2[16 + lr] * LOG2E;
#pragma unroll
    for (int r = 0; r < 4; ++r) {
        int row = row0 + quad * 4 + r;
        float g0 = acc[0][r], g1 = acc[1][r];
        float s = g0 * a2s + g1 * a2s2;
        float dd = g0 * a2d + g1 * a2d2;
#pragma unroll
        for (int m = 8; m >= 1; m >>= 1) { s += __shfl_xor(s, m); dd += __shfl_xor(dd, m); }
        if (row < N_NODES) {
            Gb[(size_t)row * 32 + lr] = f2bf(g0);
            Gb[(size_t)row * 32 + 16 + lr] = f2bf(g1);
            if (lr == 0) { als2[row] = s; ald2[row] = dd; }
        }
    }
}

// ---------------- Layer-2 aggregation: 16 lanes/node x 2 cols, pk-fma, direct v_exp ----------------

__global__ __launch_bounds__(256) void k_agg2(const unsigned short* __restrict__ Gb,
                                              const float* __restrict__ als2,
                                              const float* __restrict__ ald2_, const int* __restrict__ offp,
                                              const int* __restrict__ ecnt,
                                              const unsigned short* __restrict__ esrc, const float* __restrict__ b2,
                                              float* __restrict__ out) {
    int gid = blockIdx.x * 256 + threadIdx.x;
    int node = gid >> 4;
    int colp = gid & 15;            // cols 2*colp, 2*colp+1
    if (node >= N_NODES) return;
    float ald = ald2_[node];        // pre-scaled by LOG2E
    int pstart = offp[node];        // 4-aligned
    int pend = pstart + ecnt[node]; // real end (pads excluded)
    float l = 0.f;
    f32x2 accv = (f32x2){0.f, 0.f};

    auto edge1 = [&](int u0) {
        unsigned gpk = *(const unsigned*)(Gb + (size_t)(unsigned)u0 * 32 + 2 * colp);
        f32x2 g01 = (f32x2){asf(gpk << 16), asf(gpk & 0xffff0000u)};
        float e0 = als2[u0] + ald;
        e0 = fmaxf(e0, NEG_SLOPE * e0);
        float pw0 = __builtin_amdgcn_exp2f(e0);
        l += pw0;
        accv += (f32x2){pw0, pw0} * g01;
    };
    auto quad = [&](unsigned ua, unsigned ub) {
        int u0 = (int)(ua & 0xffffu), u1 = (int)(ua >> 16);
        int u2 = (int)(ub & 0xffffu), u3 = (int)(ub >> 16);
        unsigned g0p = *(const unsigned*)(Gb + (size_t)(unsigned)u0 * 32 + 2 * colp);
        unsigned g1p = *(const unsigned*)(Gb + (size_t)(unsigned)u1 * 32 + 2 * colp);
        unsigned g2p = *(const unsigned*)(Gb + (size_t)(unsigned)u2 * 32 + 2 * colp);
        unsigned g3p = *(const unsigned*)(Gb + (size_t)(unsigned)u3 * 32 + 2 * colp);
        f32x2 e01 = (f32x2){als2[u0], als2[u1]} + (f32x2){ald, ald};
        f32x2 e23 = (f32x2){als2[u2], als2[u3]} + (f32x2){ald, ald};
        f32x2 t01 = e01 * NEG_SLOPE, t23 = e23 * NEG_SLOPE;
        float e0 = fmaxf(e01.x, t01.x), e1 = fmaxf(e01.y, t01.y);
        float e2 = fmaxf(e23.x, t23.x), e3 = fmaxf(e23.y, t23.y);
        float pw0 = __builtin_amdgcn_exp2f(e0), pw1 = __builtin_amdgcn_exp2f(e1);
        float pw2 = __builtin_amdgcn_exp2f(e2), pw3 = __builtin_amdgcn_exp2f(e3);
        l += (pw0 + pw1) + (pw2 + pw3);
        f32x2 g0 = (f32x2){asf(g0p << 16), asf(g0p & 0xffff0000u)};
        f32x2 g1 = (f32x2){asf(g1p << 16), asf(g1p & 0xffff0000u)};
        f32x2 g2 = (f32x2){asf(g2p << 16), asf(g2p & 0xffff0000u)};
        f32x2 g3 = (f32x2){asf(g3p << 16), asf(g3p & 0xffff0000u)};
        accv += (f32x2){pw0, pw0} * g0;
        accv += (f32x2){pw1, pw1} * g1;
        accv += (f32x2){pw2, pw2} * g2;
        accv += (f32x2){pw3, pw3} * g3;
    };

    int p = pstart;
    for (; p + 7 < pend; p += 8) {
        uint2 ua = *(const uint2*)(esrc + p);
        uint2 ub = *(const uint2*)(esrc + p + 4);
        quad(ua.x, ua.y);
        quad(ub.x, ub.y);
    }
    for (; p + 3 < pend; p += 4) {
        uint2 ua = *(const uint2*)(esrc + p);
        quad(ua.x, ua.y);
    }
    for (; p < pend; ++p) edge1(esrc[p]);

    float inv = 1.f / l;
    float2 bb = *(const float2*)(b2 + 2 * colp);
    float o0 = accv.x * inv + bb.x;
    float o1 = accv.y * inv + bb.y;
    float mm = fmaxf(o0, o1);
#pragma unroll
    for (int msk = 8; msk >= 1; msk >>= 1) mm = fmaxf(mm, __shfl_xor(mm, msk));
    float s = __expf(o0 - mm) + __expf(o1 - mm);
#pragma unroll
    for (int msk = 8; msk >= 1; msk >>= 1) s += __shfl_xor(s, msk);
    float ls = logf(s);
    float2 res = make_float2(o0 - mm - ls, o1 - mm - ls);
    *(float2*)(out + (size_t)node * 32 + 2 * colp) = res;
}

// ---------------- launch ----------------

extern "C" void kernel_launch(void* const* d_in, const int* in_sizes, int n_in,
                              void* d_out, int out_size, void* d_ws, size_t ws_size,
                              hipStream_t stream) {
    const float* x   = (const float*)d_in[0];
    const int*   ei  = (const int*)d_in[1];
    const float* W1  = (const float*)d_in[2];
    const float* as1 = (const float*)d_in[3];
    const float* ad1 = (const float*)d_in[4];
    const float* b1  = (const float*)d_in[5];
    const float* W2  = (const float*)d_in[6];
    const float* as2 = (const float*)d_in[7];
    const float* ad2 = (const float*)d_in[8];
    const float* b2  = (const float*)d_in[9];
    float* out = (float*)d_out;

    char* p = (char*)d_ws;
    auto alloc = [&](size_t bytes) {
        char* r = p;
        p += (bytes + 255) & ~(size_t)255;
        return r;
    };
    // workspace ~30 MB (stage aliases h2p; g aliases h8 — disjoint lifetimes)
    unsigned char*  h8  = (unsigned char*)alloc((size_t)(N_NODES + 1) * 256);  // 12.8 MB fp8 h1 (+pad row)
    unsigned char*  h2pr= (unsigned char*)alloc((size_t)N_NODES * 64 * 4);     // 12.8 MB fp8 h2 packed
    unsigned short* wt  = (unsigned short*)alloc((size_t)256 * 256 * 2);       // 128 KB bf16 W1^T
    unsigned short* w2t = (unsigned short*)alloc((size_t)32 * 256 * 2);        // 16 KB bf16 W2^T
    float* als1 = (float*)alloc(((size_t)N_NODES * 4 + 4) * 4);                // +1 pad-sentinel row
    float* ald1 = (float*)alloc((size_t)N_NODES * 4 * 4);
    float* als2 = (float*)alloc((size_t)N_NODES * 4);
    float* ald2 = (float*)alloc((size_t)N_NODES * 4);
    int* bcur    = (int*)alloc(256 * 4);
    int* bukbase = (int*)alloc(256 * 4);
    int* offp = (int*)alloc((size_t)N_NODES * 4);
    int* ecnt = (int*)alloc((size_t)N_NODES * 4);
    unsigned short* esrc = (unsigned short*)alloc((size_t)ET_PAD_ALLOC * 2);   // 2.0 MB u16, padded CSR

    // aliases (disjoint lifetimes):
    unsigned* stage = (unsigned*)h2pr;                 // 3.6 MB (k_bin -> k_build; dead before agg1 writes h2p)
    unsigned* h2p = (unsigned*)h2pr;
    unsigned short* g = (unsigned short*)h8;           // 3.2 MB bf16 (written by gemm2m after h8 dead)

    k_cvtw<<<289, 256, 0, stream>>>(W1, W2, wt, w2t, bcur, als1, h8);          // zeroes bcur + pad rows
    k_bin<<<(N_EDGES + ACHUNK - 1) / ACHUNK, 256, 0, stream>>>(ei, bcur, stage);
    k_bukscan<<<1, 256, 0, stream>>>(bcur, bukbase);
    k_build<<<NBUK, 256, 0, stream>>>(stage, bcur, bukbase, offp, ecnt, esrc);

    k_gemm1m<<<(N_NODES + 63) / 64, 256, 0, stream>>>(x, wt, as1, ad1, h8, als1, ald1);
    k_agg1<<<N_NODES / 4, 256, 0, stream>>>((const unsigned*)h8, als1, ald1, offp, ecnt, esrc, b1, h2p);
    k_gemm2m<<<(N_NODES + 63) / 64, 256, 0, stream>>>(h2p, w2t, as2, ad2, g, als2, ald2);
    k_agg2<<<(N_NODES * 16 + 255) / 256, 256, 0, stream>>>(g, als2, ald2, offp, ecnt, esrc, b2, out);
}